// Round 14
// baseline (692.865 us; speedup 1.0000x reference)
//
#include <hip/hip_runtime.h>
#include <math.h>

#define NPTS 50000
#define MN 1024
#define KK 64
#define DPT 64
#define DN 256
#define BCORR 256
#define OUTC 1024
#define OTI 100
#define NEGV (-1e4f)
#define EPSV 1e-8f
#define CAPL 512
#define CCAP 16384
#define HB1 64     // coarse-side histogram grid/partial depth
#define RCH 2048   // rank-kernel LDS chunk

// ---------------- utility ----------------
__global__ void zero_all_kernel(int* cnt_s, int* cnt_t, int* ci_t, int* ci_s,
                                float* tpout){
  int t=blockIdx.x*256+threadIdx.x;
  if (t<MN){ cnt_s[t]=0; cnt_t[t]=0; }
  if (t<BCORR){ ci_t[t]=0; ci_s[t]=0; }
  for (int i=t;i<OUTC*3*2+OUTC;i+=gridDim.x*256) tpout[i]=0.0f;
}

__device__ __forceinline__ float blockReduceSum256(float v, float* red){
  int t=threadIdx.x;
  red[t]=v; __syncthreads();
  #pragma unroll
  for (int s=128;s>0;s>>=1){ if(t<s) red[t]+=red[t+s]; __syncthreads(); }
  float r=red[0]; __syncthreads();
  return r;
}

// node feats (fused tgt+src): out = l2norm(x @ W^T + b); sq = sum(out^2)
__global__ __launch_bounds__(256) void node_feat_kernel(
    const float* __restrict__ xt, const float* __restrict__ xs_,
    const float* __restrict__ W, const float* __restrict__ bias,
    float* __restrict__ outt, float* __restrict__ outs,
    float* __restrict__ sqt, float* __restrict__ sqs){
  __shared__ float xs[DN];
  __shared__ float red[256];
  int m=blockIdx.x, i=threadIdx.x;
  const float* x=(m<MN)? xt:xs_;
  float* out=(m<MN)? outt:outs;
  float* sq=(m<MN)? sqt:sqs;
  int mm=(m<MN)? m:m-MN;
  xs[i]=x[mm*DN+i];
  __syncthreads();
  float acc=bias[i];
  const float* wr=W+(size_t)i*DN;
  for (int k=0;k<DN;k++) acc=fmaf(wr[k],xs[k],acc);
  float ssq=blockReduceSum256(acc*acc,red);
  float o=acc/sqrtf(ssq);
  out[mm*DN+i]=o;
  float s2=blockReduceSum256(o*o,red);
  if(i==0) sq[mm]=s2;
}

// nearest node per point (fused src+tgt); nodes packed float4 (x,y,z,|n|^2)
__global__ __launch_bounds__(256) void p2n_kernel(
    const float* __restrict__ pts_s, const float* __restrict__ nd_s, int* __restrict__ o_s,
    const float* __restrict__ pts_t, const float* __restrict__ nd_t, int* __restrict__ o_t,
    int pb){
  __shared__ __align__(16) float4 nd[MN];
  int which=blockIdx.x>=pb;
  const float* pts=which? pts_t:pts_s;
  const float* nodes=which? nd_t:nd_s;
  int* p2n=which? o_t:o_s;
  int blk=which? blockIdx.x-pb : blockIdx.x;
  for (int j=threadIdx.x;j<MN;j+=256){
    float a=nodes[j*3+0], b=nodes[j*3+1], c=nodes[j*3+2];
    nd[j]=make_float4(a,b,c,a*a+b*b+c*c);
  }
  __syncthreads();
  int id=blk*256+threadIdx.x;
  if (id>=NPTS) return;
  float px=pts[id*3+0], py=pts[id*3+1], pz=pts[id*3+2];
  float pp=px*px+py*py+pz*pz;
  float best=3.4e38f; int bi=0;
  for (int j=0;j<MN;j++){
    float4 n=nd[j];
    float d=pp+n.w-2.0f*(px*n.x+py*n.y+pz*n.z);
    if (d<best){best=d;bi=j;}
  }
  p2n[id]=bi;
}

__global__ __launch_bounds__(256) void scatter_kernel(
    const int* __restrict__ p_s, int* __restrict__ c_s, int* __restrict__ l_s,
    const int* __restrict__ p_t, int* __restrict__ c_t, int* __restrict__ l_t,
    int pb){
  int which=blockIdx.x>=pb;
  const int* p2n=which? p_t:p_s;
  int* cnt=which? c_t:c_s;
  int* list=which? l_t:l_s;
  int blk=which? blockIdx.x-pb : blockIdx.x;
  int id=blk*256+threadIdx.x;
  if (id>=NPTS) return;
  int n=p2n[id];
  int t=atomicAdd(&cnt[n],1);
  if (t<CAPL) list[(size_t)n*CAPL+t]=id;
}

// per-node kNN (fused src+tgt)
__global__ __launch_bounds__(256) void knn_kernel(
    const float* __restrict__ pts_s, const float* __restrict__ nd_s,
    const int* __restrict__ c_s, const int* __restrict__ l_s, int* __restrict__ k_s,
    const float* __restrict__ pts_t, const float* __restrict__ nd_t,
    const int* __restrict__ c_t, const int* __restrict__ l_t, int* __restrict__ k_t){
  __shared__ float ds[CAPL];
  __shared__ int is[CAPL];
  int which=blockIdx.x>=MN;
  const float* pts=which? pts_t:pts_s;
  const float* nodes=which? nd_t:nd_s;
  const int* cnt=which? c_t:c_s;
  const int* list=which? l_t:l_s;
  int* knn=which? k_t:k_s;
  int m=which? blockIdx.x-MN : blockIdx.x;
  int c=cnt[m]; if (c>CAPL) c=CAPL;
  float ax=nodes[m*3+0], ay=nodes[m*3+1], az=nodes[m*3+2];
  float nn2=ax*ax+ay*ay+az*az;
  for (int e=threadIdx.x;e<c;e+=256){
    int p=list[(size_t)m*CAPL+e];
    float px=pts[p*3+0],py=pts[p*3+1],pz=pts[p*3+2];
    float pp=px*px+py*py+pz*pz;
    ds[e]=pp+nn2-2.0f*(px*ax+py*ay+pz*az);
    is[e]=p;
  }
  for (int k=threadIdx.x;k<KK;k+=256) knn[m*KK+k]=NPTS;
  __syncthreads();
  for (int e=threadIdx.x;e<c;e+=256){
    float d=ds[e]; int p=is[e]; int r=0;
    for (int j=0;j<c;j++){
      float dj=ds[j];
      r += (dj<d || (dj==d && is[j]<p)) ? 1 : 0;
    }
    if (r<KK) knn[m*KK+r]=p;
  }
}

// coarse scores as tiled GEMM
__global__ __launch_bounds__(256) void coarse_score_kernel(
    const float* __restrict__ tf, const float* __restrict__ sf,
    const float* __restrict__ tt, const float* __restrict__ ssv,
    const int* __restrict__ cnt_t, const int* __restrict__ cnt_s, float* __restrict__ S){
  __shared__ float tas[64][64];   // [k][r]
  __shared__ float sbs[64][64];   // [k][c]
  __shared__ float tta[64], ssa[64], tva[64], sva[64];
  int bi=blockIdx.x>>4, bj=blockIdx.x&15;
  int t=threadIdx.x, r=t&63, kq=t>>6, tx=t&15, ty=t>>4;
  if (kq==0){ tta[r]=tt[bi*64+r]; tva[r]=(cnt_t[bi*64+r]>0)?1.f:0.f; }
  if (kq==1){ ssa[r]=ssv[bj*64+r]; sva[r]=(cnt_s[bj*64+r]>0)?1.f:0.f; }
  float acc[4][4]={};
  const float* ta=tf+((size_t)bi*64)*DN;
  const float* sa=sf+((size_t)bj*64)*DN;
  for (int kc=0;kc<DN;kc+=64){
    __syncthreads();
    const float* tr_=ta+(size_t)r*DN+kc+kq*16;
    const float* sr_=sa+(size_t)r*DN+kc+kq*16;
    #pragma unroll
    for (int j4=0;j4<4;j4++){
      float4 v=*(const float4*)(tr_+4*j4);
      tas[kq*16+4*j4+0][r]=v.x; tas[kq*16+4*j4+1][r]=v.y;
      tas[kq*16+4*j4+2][r]=v.z; tas[kq*16+4*j4+3][r]=v.w;
      float4 w=*(const float4*)(sr_+4*j4);
      sbs[kq*16+4*j4+0][r]=w.x; sbs[kq*16+4*j4+1][r]=w.y;
      sbs[kq*16+4*j4+2][r]=w.z; sbs[kq*16+4*j4+3][r]=w.w;
    }
    __syncthreads();
    #pragma unroll
    for (int kk=0;kk<64;kk++){
      float4 a4=*(const float4*)(&tas[kk][4*ty]);
      float4 b4=*(const float4*)(&sbs[kk][4*tx]);
      float av[4]={a4.x,a4.y,a4.z,a4.w};
      float bv[4]={b4.x,b4.y,b4.z,b4.w};
      #pragma unroll
      for (int i=0;i<4;i++)
        #pragma unroll
        for (int j=0;j<4;j++) acc[i][j]=fmaf(av[i],bv[j],acc[i][j]);
    }
  }
  __syncthreads();
  #pragma unroll
  for (int i=0;i<4;i++){
    int rr=4*ty+i;
    #pragma unroll
    for (int j=0;j<4;j++){
      int cc=4*tx+j;
      float d=tta[rr]+ssa[cc]-2.0f*acc[i][j];
      float v=expf(-d);
      S[(size_t)(bi*64+rr)*MN + bj*64+cc]=(tva[rr]>0.f && sva[cc]>0.f)? v:0.0f;
    }
  }
}

// fused row+col sums
__global__ __launch_bounds__(256) void sums_kernel(
    const float* __restrict__ S, float* __restrict__ rs, float* __restrict__ cs){
  __shared__ float red[256];
  __shared__ float red2[16][17];
  if (blockIdx.x<MN){
    int i=blockIdx.x;
    float a=0;
    for (int j=threadIdx.x;j<MN;j+=256) a+=S[(size_t)i*MN+j];
    float r=blockReduceSum256(a,red);
    if (threadIdx.x==0) rs[i]=r;
  } else {
    int j0=(blockIdx.x-MN)*16;
    int tx=threadIdx.x&15, ty=threadIdx.x>>4;
    float a=0;
    for (int i=ty;i<MN;i+=16) a+=S[(size_t)i*MN + j0+tx];
    red2[ty][tx]=a; __syncthreads();
    if (ty==0){
      float s=0;
      #pragma unroll
      for (int q=0;q<16;q++) s+=red2[q][tx];
      cs[j0+tx]=s;
    }
  }
}
// dual normalization fused with L1 histogram pass -> partial1 (HB1 blocks)
__global__ __launch_bounds__(256) void dualnorm_hist_kernel(
    float* __restrict__ S, const float* __restrict__ rs, const float* __restrict__ cs,
    unsigned* __restrict__ partial1){
  __shared__ unsigned lh[256];
  lh[threadIdx.x]=0u; __syncthreads();
  for (int idx=blockIdx.x*256+threadIdx.x; idx<MN*MN; idx+=gridDim.x*256){
    int i=idx>>10, j=idx&1023;
    float v=S[idx];
    v=(v/(rs[i]+EPSV))*(v/(cs[j]+EPSV));
    S[idx]=v;
    if (v>0.0f) atomicAdd(&lh[__float_as_uint(v)>>24],1u);
  }
  __syncthreads();
  partial1[blockIdx.x*256+threadIdx.x]=lh[threadIdx.x];
}

// ---------- deterministic top-k, three-level histogram (scans fused) ----------
__device__ __forceinline__ int scan_top(const unsigned* h, int k, unsigned start,
                                        unsigned* outcum){
  unsigned cum=start;
  for (int b=255;b>=0;b--){
    if (cum+h[b] >= (unsigned)k){ *outcum=cum; return b; }
    cum+=h[b];
  }
  *outcum=cum;
  return -1;
}
__device__ __forceinline__ void sum_partials(const unsigned* __restrict__ p,
                                             unsigned* h, int t, int nblk){
  unsigned a=0;
  for (int i=0;i<nblk;i++) a+=p[(size_t)i*256+t];
  h[t]=a;
}

// L2 histogram; per-block inline L1 scan
__global__ __launch_bounds__(256) void hist_fine_kernel(
    const float* __restrict__ arr, int n, int k,
    const unsigned* __restrict__ p1, int n1, unsigned* __restrict__ p2){
  __shared__ unsigned h[256];
  __shared__ unsigned lh[256];
  __shared__ unsigned cbS;
  int t=threadIdx.x;
  lh[t]=0u;
  sum_partials(p1,h,t,n1);
  __syncthreads();
  if (t==0){
    unsigned ab; int cb=scan_top(h,k,0u,&ab);
    if (cb<0) cb=0;
    cbS=(unsigned)cb;
  }
  __syncthreads();
  unsigned CB=cbS;
  for (int i=blockIdx.x*256+t; i<n; i+=gridDim.x*256){
    float v=arr[i];
    unsigned b=__float_as_uint(v);
    if (v>0.0f && (b>>24)==CB) atomicAdd(&lh[(b>>16)&255u],1u);
  }
  __syncthreads();
  p2[blockIdx.x*256+t]=lh[t];
}
// L3 histogram; per-block inline L1+L2 scans; block0 resets cand counter
__global__ __launch_bounds__(256) void hist_fine2_kernel(
    const float* __restrict__ arr, int n, int k,
    const unsigned* __restrict__ p1, int n1,
    const unsigned* __restrict__ p2, int n2,
    unsigned* __restrict__ p3, unsigned* __restrict__ cnt){
  __shared__ unsigned h[256];
  __shared__ unsigned lh[256];
  __shared__ unsigned t16S;
  int t=threadIdx.x;
  if (blockIdx.x==0 && t==0) *cnt=0u;
  lh[t]=0u;
  sum_partials(p1,h,t,n1);
  __syncthreads();
  __shared__ unsigned cbS, ab1S;
  if (t==0){
    unsigned ab; int cb=scan_top(h,k,0u,&ab);
    if (cb<0){ cb=0; ab=ab-h[0]; }
    cbS=(unsigned)cb; ab1S=ab;
  }
  __syncthreads();
  sum_partials(p2,h,t,n2);
  __syncthreads();
  if (t==0){
    unsigned ab2; int sb=scan_top(h,k,ab1S,&ab2);
    if (sb<0) sb=0;
    t16S=cbS*256u+(unsigned)sb;
  }
  __syncthreads();
  unsigned T16=t16S;
  for (int i=blockIdx.x*256+t; i<n; i+=gridDim.x*256){
    float v=arr[i];
    unsigned b=__float_as_uint(v);
    if (v>0.0f && (b>>16)==T16) atomicAdd(&lh[(b>>8)&255u],1u);
  }
  __syncthreads();
  p3[blockIdx.x*256+t]=lh[t];
}
// compact with inline L1+L2+L3 scans
__global__ __launch_bounds__(256) void compact_kernel(
    const float* __restrict__ arr, int n, int k,
    const unsigned* __restrict__ p1, int n1,
    const unsigned* __restrict__ p2, int n2,
    const unsigned* __restrict__ p3, int n3,
    float* __restrict__ cv, int* __restrict__ ci, unsigned* __restrict__ cnt){
  __shared__ unsigned h[256];
  __shared__ unsigned cbS, ab1S, t16S, ab2S, t24S;
  int t=threadIdx.x;
  sum_partials(p1,h,t,n1);
  __syncthreads();
  if (t==0){
    unsigned ab; int cb=scan_top(h,k,0u,&ab);
    if (cb<0){ cb=0; ab=ab-h[0]; }
    cbS=(unsigned)cb; ab1S=ab;
  }
  __syncthreads();
  sum_partials(p2,h,t,n2);
  __syncthreads();
  if (t==0){
    unsigned ab2; int sb=scan_top(h,k,ab1S,&ab2);
    if (sb<0) sb=0;
    t16S=cbS*256u+(unsigned)sb; ab2S=ab2;
  }
  __syncthreads();
  sum_partials(p3,h,t,n3);
  __syncthreads();
  if (t==0){
    unsigned ab3; int sb=scan_top(h,k,ab2S,&ab3);
    if (sb<0) sb=0;
    t24S=t16S*256u+(unsigned)sb;
  }
  __syncthreads();
  unsigned T=t24S;
  for (int i=blockIdx.x*256+t; i<n; i+=gridDim.x*256){
    float v=arr[i];
    if (v>0.0f && (__float_as_uint(v)>>8)>=T){
      unsigned p=atomicAdd(cnt,1u);
      if (p<CCAP){ cv[p]=v; ci[p]=i; }
    }
  }
}
// LDS-tiled exact rank (value desc, index asc)
__global__ __launch_bounds__(256) void rank_coarse_kernel(
    const float* __restrict__ cv, const int* __restrict__ ci, const unsigned* __restrict__ meta,
    int* __restrict__ ti, int* __restrict__ si){
  __shared__ __align__(16) float scv[RCH];
  __shared__ __align__(16) int sci[RCH];
  int c=(int)meta[1]; if (c>CCAP) c=CCAP;
  int t=blockIdx.x*256+threadIdx.x;
  bool act=(t<c);
  float v=0.0f; int idx=0;
  if (act){ v=cv[t]; idx=ci[t]; }
  int rk=0;
  for (int base=0;base<c;base+=RCH){
    int lim=min(RCH,c-base);
    __syncthreads();
    for (int j=threadIdx.x;j<lim;j+=256){ scv[j]=cv[base+j]; sci[j]=ci[base+j]; }
    __syncthreads();
    if (act){
      int j=0;
      for (;j+4<=lim;j+=4){
        float4 v4=*(const float4*)(scv+j);
        int4 i4=*(const int4*)(sci+j);
        rk += (v4.x>v||(v4.x==v&&i4.x<idx))?1:0;
        rk += (v4.y>v||(v4.y==v&&i4.y<idx))?1:0;
        rk += (v4.z>v||(v4.z==v&&i4.z<idx))?1:0;
        rk += (v4.w>v||(v4.w==v&&i4.w<idx))?1:0;
      }
      for (;j<lim;j++) rk += (scv[j]>v||(scv[j]==v&&sci[j]<idx))?1:0;
    }
  }
  if (act && rk<BCORR){ ti[rk]=idx/MN; si[rk]=idx%MN; }
}
__global__ __launch_bounds__(256) void rank_fine_kernel(
    const float* __restrict__ cv, const int* __restrict__ ci, const unsigned* __restrict__ meta,
    const int* __restrict__ sel_t, const int* __restrict__ sel_s,
    const float* __restrict__ tpts, const float* __restrict__ spts,
    float* __restrict__ tp, float* __restrict__ sp, float* __restrict__ cs){
  __shared__ __align__(16) float scv[RCH];
  __shared__ __align__(16) int sci[RCH];
  int c=(int)meta[1]; if (c>CCAP) c=CCAP;
  int t=blockIdx.x*256+threadIdx.x;
  bool act=(t<c);
  float v=0.0f; int idx=0;
  if (act){ v=cv[t]; idx=ci[t]; }
  int rk=0;
  for (int base=0;base<c;base+=RCH){
    int lim=min(RCH,c-base);
    __syncthreads();
    for (int j=threadIdx.x;j<lim;j+=256){ scv[j]=cv[base+j]; sci[j]=ci[base+j]; }
    __syncthreads();
    if (act){
      int j=0;
      for (;j+4<=lim;j+=4){
        float4 v4=*(const float4*)(scv+j);
        int4 i4=*(const int4*)(sci+j);
        rk += (v4.x>v||(v4.x==v&&i4.x<idx))?1:0;
        rk += (v4.y>v||(v4.y==v&&i4.y<idx))?1:0;
        rk += (v4.z>v||(v4.z==v&&i4.z<idx))?1:0;
        rk += (v4.w>v||(v4.w==v&&i4.w<idx))?1:0;
      }
      for (;j<lim;j++) rk += (scv[j]>v||(scv[j]==v&&sci[j]<idx))?1:0;
    }
  }
  if (act && rk<OUTC){
    int b=idx>>12, r=(idx>>6)&63, cc=idx&63;
    int tpi=sel_t[b*KK+r], spi=sel_s[b*KK+cc];
    float tx=0,ty=0,tz=0,sx=0,sy=0,sz=0;
    if (tpi<NPTS){ tx=tpts[tpi*3]; ty=tpts[tpi*3+1]; tz=tpts[tpi*3+2]; }
    if (spi<NPTS){ sx=spts[spi*3]; sy=spts[spi*3+1]; sz=spts[spi*3+2]; }
    tp[rk*3+0]=tx; tp[rk*3+1]=ty; tp[rk*3+2]=tz;
    sp[rk*3+0]=sx; sp[rk*3+1]=sy; sp[rk*3+2]=sz;
    cs[rk]=v;
  }
}

// ---------- patch assembly ----------
__global__ __launch_bounds__(256) void sel_feat_kernel(
    const int* __restrict__ ci_t, const int* __restrict__ knn_t, const float* __restrict__ ptf_t,
    const int* __restrict__ ci_s, const int* __restrict__ knn_s, const float* __restrict__ ptf_s,
    const float* __restrict__ W, const float* __restrict__ bias,
    float* __restrict__ out_t, float* __restrict__ out_s,
    int* __restrict__ sel_tO, int* __restrict__ sel_sO){
  __shared__ float Xs[64][64];   // [k][r]
  __shared__ float Ws[64][64];   // [k][o]
  __shared__ float pvf[64];
  int which=blockIdx.x>=1024;
  const int* cib=which? ci_s:ci_t;
  const int* knn=which? knn_s:knn_t;
  const float* ptf=which? ptf_s:ptf_t;
  float* out=which? out_s:out_t;
  int* sel=which? sel_sO:sel_tO;
  int blk=which? blockIdx.x-1024 : blockIdx.x;
  int bj=blk>>2, bo=blk&3;
  int t=threadIdx.x, r=t&63, kq=t>>6, tx=t&15, ty=t>>4;
  int p=knn[cib[bj]*KK+r];
  if (kq==0){
    pvf[r]=(p!=NPTS)?1.f:0.f;
    if (bo==0) sel[bj*KK+r]=p;
  }
  const float* xr=ptf+(size_t)p*DPT+kq*16;
  #pragma unroll
  for (int j4=0;j4<4;j4++){
    float4 v=(p==NPTS)? make_float4(0.f,0.f,0.f,0.f) : *(const float4*)(xr+4*j4);
    Xs[kq*16+4*j4+0][r]=v.x; Xs[kq*16+4*j4+1][r]=v.y;
    Xs[kq*16+4*j4+2][r]=v.z; Xs[kq*16+4*j4+3][r]=v.w;
  }
  const float* wr=W+(size_t)(bo*64+r)*DPT+kq*16;
  #pragma unroll
  for (int j4=0;j4<4;j4++){
    float4 w=*(const float4*)(wr+4*j4);
    Ws[kq*16+4*j4+0][r]=w.x; Ws[kq*16+4*j4+1][r]=w.y;
    Ws[kq*16+4*j4+2][r]=w.z; Ws[kq*16+4*j4+3][r]=w.w;
  }
  __syncthreads();
  float acc[4][4]={};
  #pragma unroll
  for (int kk=0;kk<64;kk++){
    float4 a4=*(const float4*)(&Xs[kk][4*ty]);
    float4 w4=*(const float4*)(&Ws[kk][4*tx]);
    float av[4]={a4.x,a4.y,a4.z,a4.w};
    float wv[4]={w4.x,w4.y,w4.z,w4.w};
    #pragma unroll
    for (int i=0;i<4;i++)
      #pragma unroll
      for (int j=0;j<4;j++) acc[i][j]=fmaf(av[i],wv[j],acc[i][j]);
  }
  #pragma unroll
  for (int i=0;i<4;i++){
    int rr=4*ty+i;
    #pragma unroll
    for (int j=0;j<4;j++){
      int oo=4*tx+j;
      float v=acc[i][j]+bias[bo*64+oo];
      out[(size_t)(bj*64+rr)*DN + bo*64+oo]= (pvf[rr]>0.f)? v : 0.0f;
    }
  }
}

// ===== FUSED pbuild + Sinkhorn(R12 column-split) + fineprep =====
// Phase 1: 64x64x256 GEMM -> Ps in LDS (with mask/dustbin).
// Phase 2: linear-domain Sinkhorn, 4 waves column-split, readlane broadcasts,
//          2 barriers/iter (the round-12 schedule, reverted verbatim).
// Phase 3: ms = Ps+u+v-nrm written to global once; s=exp(ms) feeds the
//          mutual-top3 fine prep + L1 histogram — no global round-trips.
__global__ __launch_bounds__(256,1) void pot_kernel(
    const float* __restrict__ ft, const float* __restrict__ fs,
    const int* __restrict__ sel_t, const int* __restrict__ sel_s,
    const float* __restrict__ alpha_p,
    float* __restrict__ msout, float* __restrict__ smout,
    unsigned* __restrict__ partial1){
  __shared__ float tas[64][64];
  __shared__ float sbs[64][64];
  __shared__ float tmv[64], smv[64];
  __shared__ float Ps[4225];
  __shared__ __align__(16) float partU[4][72], partV[4][72];
  __shared__ __align__(16) float pu64[4], pusv[4], pv64[4], pvsv[4];
  __shared__ float ufs[65], vfs[65];
  __shared__ float sm[KK*KK];
  __shared__ unsigned long long rowm[KK], colm[KK];
  __shared__ unsigned lh[256];
  int b=blockIdx.x, t=threadIdx.x, w=t>>6, l=t&63;
  int r=t&63, kq=t>>6, tx=t&15, ty=t>>4;
  // ---------- phase 1: pbuild into LDS ----------
  if (kq==0) tmv[r]=(sel_t[b*KK+r]!=NPTS)?1.f:0.f;
  if (kq==1) smv[r]=(sel_s[b*KK+r]!=NPTS)?1.f:0.f;
  float acc[4][4]={};
  const float* tb=ft+(size_t)b*KK*DN;
  const float* sb=fs+(size_t)b*KK*DN;
  for (int kc=0;kc<DN;kc+=64){
    __syncthreads();
    const float* tr_=tb+(size_t)r*DN+kc+kq*16;
    const float* sr_=sb+(size_t)r*DN+kc+kq*16;
    #pragma unroll
    for (int j4=0;j4<4;j4++){
      float4 v=*(const float4*)(tr_+4*j4);
      tas[kq*16+4*j4+0][r]=v.x; tas[kq*16+4*j4+1][r]=v.y;
      tas[kq*16+4*j4+2][r]=v.z; tas[kq*16+4*j4+3][r]=v.w;
      float4 wv4=*(const float4*)(sr_+4*j4);
      sbs[kq*16+4*j4+0][r]=wv4.x; sbs[kq*16+4*j4+1][r]=wv4.y;
      sbs[kq*16+4*j4+2][r]=wv4.z; sbs[kq*16+4*j4+3][r]=wv4.w;
    }
    __syncthreads();
    #pragma unroll
    for (int kk=0;kk<64;kk++){
      float4 a4=*(const float4*)(&tas[kk][4*ty]);
      float4 b4=*(const float4*)(&sbs[kk][4*tx]);
      float av[4]={a4.x,a4.y,a4.z,a4.w};
      float bv[4]={b4.x,b4.y,b4.z,b4.w};
      #pragma unroll
      for (int i=0;i<4;i++)
        #pragma unroll
        for (int j=0;j<4;j++) acc[i][j]=fmaf(av[i],bv[j],acc[i][j]);
    }
  }
  __syncthreads();
  float alpha=alpha_p[0];
  #pragma unroll
  for (int i=0;i<4;i++){
    int rr=4*ty+i;
    bool tok=tmv[rr]>0.f;
    #pragma unroll
    for (int j=0;j<4;j++){
      int cc=4*tx+j;
      bool invm=(!tok)||(smv[cc]<=0.f);
      Ps[rr*65+cc]= invm ? NEGV : acc[i][j]*0.0625f;
    }
  }
  if (t<64){
    Ps[64*65+t]=(smv[t]<=0.f)? NEGV : alpha;
    Ps[t*65+64]=(tmv[t]<=0.f)? NEGV : alpha;
  }
  if (t==64) Ps[4224]=alpha;
  __syncthreads();
  // ---------- phase 2: Sinkhorn (round-12 schedule) ----------
  bool rv=(tmv[l]>0.f);
  bool cv=(smv[l]>0.f);
  int nr=(int)__popcll(__ballot(rv));
  int nc=(int)__popcll(__ballot(cv));
  float inv=1.0f/(float)(nr+nc);
  float nrm=-logf((float)(nr+nc));
  float mu_l=inv, nu_l=inv, mu64=(float)nc*inv, nu64=(float)nr*inv;
  bool anyInvR=(nr<KK), anyInvC=(nc<KK);
  const int c0=16*w;
  float aQ[16], bQ[16], r64Q[16], c64Q[16];
  #pragma unroll
  for (int j=0;j<16;j++){
    aQ[j]  =expf(Ps[l*65+c0+j]);
    bQ[j]  =expf(Ps[(c0+j)*65+l]);
    r64Q[j]=expf(Ps[64*65+c0+j]);
    c64Q[j]=expf(Ps[(c0+j)*65+64]);
  }
  float a64=expf(Ps[l*65+64]);
  float b64v=expf(Ps[64*65+l]);
  float k6464=expf(Ps[4224]);
  float U_l, V_l=1.0f, U64, V64=1.0f;

  for (int it=0; it<OTI; ++it){
    float p0=0,p1f=0,p2f=0,p3=0, d0=0,d1=0,d2=0,d3=0, z0=0,z1=0,z2=0,z3=0;
    #pragma unroll
    for (int j4=0;j4<4;j4++){
      float v0=__int_as_float(__builtin_amdgcn_readlane(__float_as_int(V_l), c0+4*j4+0));
      float v1=__int_as_float(__builtin_amdgcn_readlane(__float_as_int(V_l), c0+4*j4+1));
      float v2=__int_as_float(__builtin_amdgcn_readlane(__float_as_int(V_l), c0+4*j4+2));
      float v3=__int_as_float(__builtin_amdgcn_readlane(__float_as_int(V_l), c0+4*j4+3));
      p0=fmaf(aQ[4*j4+0],v0,p0); p1f=fmaf(aQ[4*j4+1],v1,p1f);
      p2f=fmaf(aQ[4*j4+2],v2,p2f); p3=fmaf(aQ[4*j4+3],v3,p3);
      d0=fmaf(r64Q[4*j4+0],v0,d0); d1=fmaf(r64Q[4*j4+1],v1,d1);
      d2=fmaf(r64Q[4*j4+2],v2,d2); d3=fmaf(r64Q[4*j4+3],v3,d3);
      z0+=v0; z1+=v1; z2+=v2; z3+=v3;
    }
    partU[w][l]=(p0+p1f)+(p2f+p3);
    if (l==0){ pu64[w]=(d0+d1)+(d2+d3); pusv[w]=(z0+z1)+(z2+z3); }
    __syncthreads();
    {
      float s=partU[0][l]+partU[1][l]+partU[2][l]+partU[3][l];
      float4 d4=*(const float4*)pu64;
      float srow=s+a64*V64;
      float s64=(d4.x+d4.y)+(d4.z+d4.w)+k6464*V64;
      U64=mu64/s64;
      if (anyInvR){
        float4 z4=*(const float4*)pusv;
        float sv=(z4.x+z4.y)+(z4.z+z4.w)+V64;
        U_l = rv ? (mu_l/srow) : (1.0f/sv);
      } else U_l = mu_l/srow;
    }
    float q0=0,q1=0,q2=0,q3=0, e0=0,e1=0,e2=0,e3=0, y0=0,y1=0,y2=0,y3=0;
    #pragma unroll
    for (int j4=0;j4<4;j4++){
      float u0=__int_as_float(__builtin_amdgcn_readlane(__float_as_int(U_l), c0+4*j4+0));
      float u1=__int_as_float(__builtin_amdgcn_readlane(__float_as_int(U_l), c0+4*j4+1));
      float u2=__int_as_float(__builtin_amdgcn_readlane(__float_as_int(U_l), c0+4*j4+2));
      float u3=__int_as_float(__builtin_amdgcn_readlane(__float_as_int(U_l), c0+4*j4+3));
      q0=fmaf(bQ[4*j4+0],u0,q0); q1=fmaf(bQ[4*j4+1],u1,q1);
      q2=fmaf(bQ[4*j4+2],u2,q2); q3=fmaf(bQ[4*j4+3],u3,q3);
      e0=fmaf(c64Q[4*j4+0],u0,e0); e1=fmaf(c64Q[4*j4+1],u1,e1);
      e2=fmaf(c64Q[4*j4+2],u2,e2); e3=fmaf(c64Q[4*j4+3],u3,e3);
      y0+=u0; y1+=u1; y2+=u2; y3+=u3;
    }
    partV[w][l]=(q0+q1)+(q2+q3);
    if (l==0){ pv64[w]=(e0+e1)+(e2+e3); pvsv[w]=(y0+y1)+(y2+y3); }
    __syncthreads();
    {
      float sc=partV[0][l]+partV[1][l]+partV[2][l]+partV[3][l];
      float4 e4=*(const float4*)pv64;
      float scol=sc+b64v*U64;
      float s64v=(e4.x+e4.y)+(e4.z+e4.w)+k6464*U64;
      V64=nu64/s64v;
      if (anyInvC){
        float4 y4=*(const float4*)pvsv;
        float su=(y4.x+y4.y)+(y4.z+y4.w)+U64;
        V_l = cv ? (nu_l/scol) : (1.0f/su);
      } else V_l = nu_l/scol;
    }
  }
  if (w==0){
    ufs[l]=logf(U_l); vfs[l]=logf(V_l);
    if (l==0){ ufs[64]=logf(U64); vfs[64]=logf(V64); }
  }
  lh[t]=0u;
  __syncthreads();
  // ---------- phase 3: write ms + fine prep from LDS ----------
  float* Pg=msout+(size_t)b*4225;
  for (int e=t;e<4225;e+=256){
    int rr=e/65, cc=e-65*rr;
    float msv=Ps[e]+ufs[rr]+vfs[cc]-nrm;
    Pg[e]=msv;
    if (rr<KK && cc<KK) sm[rr*KK+cc]=expf(msv);
  }
  __syncthreads();
  if (t<KK){
    float v1=-1,v2=-1,v3=-1; int i1=0,i2=0,i3=0;
    const float* row=sm+t*KK;
    for (int c=0;c<KK;c++){ float v=row[c];
      if (v>v1){v3=v2;i3=i2;v2=v1;i2=i1;v1=v;i1=c;}
      else if (v>v2){v3=v2;i3=i2;v2=v;i2=c;}
      else if (v>v3){v3=v;i3=c;}
    }
    rowm[t]=(1ULL<<i1)|(1ULL<<i2)|(1ULL<<i3);
  } else if (t<2*KK){
    int c=t-KK;
    float v1=-1,v2=-1,v3=-1; int i1=0,i2=0,i3=0;
    for (int rr=0;rr<KK;rr++){ float v=sm[rr*KK+c];
      if (v>v1){v3=v2;i3=i2;v2=v1;i2=i1;v1=v;i1=rr;}
      else if (v>v2){v3=v2;i3=i2;v2=v;i2=rr;}
      else if (v>v3){v3=v;i3=rr;}
    }
    colm[c]=(1ULL<<i1)|(1ULL<<i2)|(1ULL<<i3);
  }
  __syncthreads();
  for (int e=t;e<KK*KK;e+=256){
    int rr=e>>6, cc=e&63;
    float v=sm[e];
    bool keep = ((rowm[rr]>>cc)&1ULL) && ((colm[cc]>>rr)&1ULL) && (v>0.05f)
                && (tmv[rr]>0.f) && (smv[cc]>0.f);
    float o= keep? v : 0.0f;
    smout[(size_t)b*KK*KK+e]=o;
    if (o>0.0f) atomicAdd(&lh[__float_as_uint(o)>>24],1u);
  }
  __syncthreads();
  partial1[b*256+t]=lh[t];
}

extern "C" void kernel_launch(void* const* d_in, const int* in_sizes, int n_in,
                              void* d_out, int out_size, void* d_ws, size_t ws_size,
                              hipStream_t stream){
  const float* src_pts=(const float*)d_in[0];
  const float* tgt_pts=(const float*)d_in[1];
  const float* src_pf =(const float*)d_in[2];
  const float* tgt_pf =(const float*)d_in[3];
  const float* src_nf =(const float*)d_in[4];
  const float* tgt_nf =(const float*)d_in[5];
  const float* src_nx =(const float*)d_in[6];
  const float* tgt_nx =(const float*)d_in[7];
  const float* cw=(const float*)d_in[8];
  const float* cb=(const float*)d_in[9];
  const float* fw=(const float*)d_in[10];
  const float* fb=(const float*)d_in[11];
  const float* alpha=(const float*)d_in[12];

  char* ws=(char*)d_ws;
  size_t off=0;
  auto A=[&](size_t bytes)->char*{
    char* p=ws+off; off+=(bytes+255)&~(size_t)255; return p; };

  float* tf    =(float*)A((size_t)MN*DN*4);
  float* sfb   =(float*)A((size_t)MN*DN*4);
  float* tt    =(float*)A(MN*4);
  float* ssv   =(float*)A(MN*4);
  int*   p2n_s =(int*)A((size_t)NPTS*4);
  int*   p2n_t =(int*)A((size_t)NPTS*4);
  int*   cnt_s =(int*)A(MN*4);
  int*   cnt_t =(int*)A(MN*4);
  int*   list_s=(int*)A((size_t)MN*CAPL*4);
  int*   list_t=(int*)A((size_t)MN*CAPL*4);
  int*   knn_s =(int*)A((size_t)MN*KK*4);
  int*   knn_t =(int*)A((size_t)MN*KK*4);
  float* Smat  =(float*)A((size_t)MN*MN*4);
  unsigned* partial1=(unsigned*)A((size_t)256*256*4);
  unsigned* partial2=(unsigned*)A((size_t)256*256*4);
  unsigned* partial3=(unsigned*)A((size_t)256*256*4);
  unsigned* meta=(unsigned*)A(256);
  float* cand_v=(float*)A((size_t)CCAP*4);
  int*   cand_i=(int*)A((size_t)CCAP*4);
  int*   ci_t  =(int*)A(BCORR*4);
  int*   ci_s  =(int*)A(BCORR*4);
  int*   sel_t =(int*)A((size_t)BCORR*KK*4);
  int*   sel_s =(int*)A((size_t)BCORR*KK*4);
  float* feat_t=(float*)A((size_t)BCORR*KK*DN*4);
  float* feat_s=(float*)A((size_t)BCORR*KK*DN*4);
  float* smf   =(float*)A((size_t)BCORR*KK*KK*4);
  float* rs    =(float*)A(MN*4);
  float* csum  =(float*)A(MN*4);

  float* out=(float*)d_out;
  float* msout=out;
  float* tpout=out+(size_t)BCORR*65*65;
  float* spout=tpout+(size_t)OUTC*3;
  float* csout=spout+(size_t)OUTC*3;

  const int PB=(NPTS+255)/256;

  zero_all_kernel<<<28,256,0,stream>>>(cnt_s,cnt_t,ci_t,ci_s,tpout);
  node_feat_kernel<<<2*MN,256,0,stream>>>(tgt_nf,src_nf,cw,cb,tf,sfb,tt,ssv);
  p2n_kernel<<<2*PB,256,0,stream>>>(src_pts,src_nx,p2n_s,tgt_pts,tgt_nx,p2n_t,PB);
  scatter_kernel<<<2*PB,256,0,stream>>>(p2n_s,cnt_s,list_s,p2n_t,cnt_t,list_t,PB);
  knn_kernel<<<2*MN,256,0,stream>>>(src_pts,src_nx,cnt_s,list_s,knn_s,
                                    tgt_pts,tgt_nx,cnt_t,list_t,knn_t);

  coarse_score_kernel<<<256,256,0,stream>>>(tf,sfb,tt,ssv,cnt_t,cnt_s,Smat);
  sums_kernel<<<MN+64,256,0,stream>>>(Smat,rs,csum);
  dualnorm_hist_kernel<<<HB1,256,0,stream>>>(Smat,rs,csum,partial1);

  hist_fine_kernel<<<HB1,256,0,stream>>>(Smat,MN*MN,BCORR,partial1,HB1,partial2);
  hist_fine2_kernel<<<HB1,256,0,stream>>>(Smat,MN*MN,BCORR,partial1,HB1,partial2,HB1,
                                          partial3,meta+1);
  compact_kernel<<<HB1,256,0,stream>>>(Smat,MN*MN,BCORR,partial1,HB1,partial2,HB1,
                                       partial3,HB1,cand_v,cand_i,meta+1);
  rank_coarse_kernel<<<CCAP/256,256,0,stream>>>(cand_v,cand_i,meta,ci_t,ci_s);

  sel_feat_kernel<<<2048,256,0,stream>>>(ci_t,knn_t,tgt_pf, ci_s,knn_s,src_pf,
                                         fw,fb,feat_t,feat_s,sel_t,sel_s);

  pot_kernel<<<BCORR,256,0,stream>>>(feat_t,feat_s,sel_t,sel_s,alpha,
                                     msout,smf,partial1);

  hist_fine_kernel<<<HB1,256,0,stream>>>(smf,BCORR*KK*KK,OUTC,partial1,256,partial2);
  hist_fine2_kernel<<<HB1,256,0,stream>>>(smf,BCORR*KK*KK,OUTC,partial1,256,partial2,HB1,
                                          partial3,meta+1);
  compact_kernel<<<HB1,256,0,stream>>>(smf,BCORR*KK*KK,OUTC,partial1,256,partial2,HB1,
                                       partial3,HB1,cand_v,cand_i,meta+1);
  rank_fine_kernel<<<CCAP/256,256,0,stream>>>(cand_v,cand_i,meta,sel_t,sel_s,
                                              tgt_pts,src_pts,tpout,spout,csout);
}

// Round 15
// 541.394 us; speedup vs baseline: 1.2798x; 1.2798x over previous
//
#include <hip/hip_runtime.h>
#include <math.h>

#define NPTS 50000
#define MN 1024
#define KK 64
#define DPT 64
#define DN 256
#define BCORR 256
#define OUTC 1024
#define OTI 100
#define NEGV (-1e4f)
#define EPSV 1e-8f
#define CAPL 512
#define CCAP 16384
#define HBLK 256   // blocks for histogram passes (and partial-buffer depth)
#define RCH 2048   // rank-kernel LDS chunk

// ---------------- utility ----------------
__global__ void zero_all_kernel(int* cnt_s, int* cnt_t, int* ci_t, int* ci_s,
                                float* tpout){
  int t=blockIdx.x*256+threadIdx.x;
  if (t<MN){ cnt_s[t]=0; cnt_t[t]=0; }
  if (t<BCORR){ ci_t[t]=0; ci_s[t]=0; }
  for (int i=t;i<OUTC*3*2+OUTC;i+=gridDim.x*256) tpout[i]=0.0f;
}

__device__ __forceinline__ float blockReduceSum256(float v, float* red){
  int t=threadIdx.x;
  red[t]=v; __syncthreads();
  #pragma unroll
  for (int s=128;s>0;s>>=1){ if(t<s) red[t]+=red[t+s]; __syncthreads(); }
  float r=red[0]; __syncthreads();
  return r;
}

// node feature GEMM: raw = [X_tgt;X_src](2048x256) @ W^T + b  (tiled, coalesced)
// grid 128 = 32 row-tiles x 4 col-tiles
__global__ __launch_bounds__(256) void node_gemm_kernel(
    const float* __restrict__ xt, const float* __restrict__ xs_,
    const float* __restrict__ W, const float* __restrict__ bias,
    float* __restrict__ raw){
  __shared__ float Xs[64][64];   // [k][r]
  __shared__ float Ws[64][64];   // [k][o]
  int bi=blockIdx.x>>2, bo=blockIdx.x&3;
  const float* x=(bi<16)? xt:xs_;
  int rowbase=(bi&15)*64;
  int t=threadIdx.x, r=t&63, kq=t>>6, tx=t&15, ty=t>>4;
  float acc[4][4]={};
  for (int kc=0;kc<DN;kc+=64){
    __syncthreads();
    const float* xr=x+(size_t)(rowbase+r)*DN+kc+kq*16;
    const float* wr=W+(size_t)(bo*64+r)*DN+kc+kq*16;
    #pragma unroll
    for (int j4=0;j4<4;j4++){
      float4 v=*(const float4*)(xr+4*j4);
      Xs[kq*16+4*j4+0][r]=v.x; Xs[kq*16+4*j4+1][r]=v.y;
      Xs[kq*16+4*j4+2][r]=v.z; Xs[kq*16+4*j4+3][r]=v.w;
      float4 w=*(const float4*)(wr+4*j4);
      Ws[kq*16+4*j4+0][r]=w.x; Ws[kq*16+4*j4+1][r]=w.y;
      Ws[kq*16+4*j4+2][r]=w.z; Ws[kq*16+4*j4+3][r]=w.w;
    }
    __syncthreads();
    #pragma unroll
    for (int kk=0;kk<64;kk++){
      float4 a4=*(const float4*)(&Xs[kk][4*ty]);
      float4 w4=*(const float4*)(&Ws[kk][4*tx]);
      float av[4]={a4.x,a4.y,a4.z,a4.w};
      float wv[4]={w4.x,w4.y,w4.z,w4.w};
      #pragma unroll
      for (int i=0;i<4;i++)
        #pragma unroll
        for (int j=0;j<4;j++) acc[i][j]=fmaf(av[i],wv[j],acc[i][j]);
    }
  }
  size_t gr=(size_t)(bi*64)*DN;
  #pragma unroll
  for (int i=0;i<4;i++){
    int rr=4*ty+i;
    #pragma unroll
    for (int j=0;j<4;j++){
      int oo=4*tx+j;
      raw[gr+(size_t)rr*DN+bo*64+oo]=acc[i][j]+bias[bo*64+oo];
    }
  }
}
// normalize: out = raw/||raw||, sq = sum(out^2); rows 0..1023 tgt, 1024.. src
__global__ __launch_bounds__(256) void node_norm_kernel(
    const float* __restrict__ raw,
    float* __restrict__ outt, float* __restrict__ outs,
    float* __restrict__ sqt, float* __restrict__ sqs){
  __shared__ float red[256];
  int m=blockIdx.x, i=threadIdx.x;
  float* out=(m<MN)? outt:outs;
  float* sq=(m<MN)? sqt:sqs;
  int mm=(m<MN)? m:m-MN;
  float acc=raw[(size_t)m*DN+i];
  float ssq=blockReduceSum256(acc*acc,red);
  float o=acc/sqrtf(ssq);
  out[mm*DN+i]=o;
  float s2=blockReduceSum256(o*o,red);
  if(i==0) sq[mm]=s2;
}

// nearest node per point (fused src+tgt); nodes packed float4 (x,y,z,|n|^2)
__global__ __launch_bounds__(256) void p2n_kernel(
    const float* __restrict__ pts_s, const float* __restrict__ nd_s, int* __restrict__ o_s,
    const float* __restrict__ pts_t, const float* __restrict__ nd_t, int* __restrict__ o_t,
    int pb){
  __shared__ __align__(16) float4 nd[MN];
  int which=blockIdx.x>=pb;
  const float* pts=which? pts_t:pts_s;
  const float* nodes=which? nd_t:nd_s;
  int* p2n=which? o_t:o_s;
  int blk=which? blockIdx.x-pb : blockIdx.x;
  for (int j=threadIdx.x;j<MN;j+=256){
    float a=nodes[j*3+0], b=nodes[j*3+1], c=nodes[j*3+2];
    nd[j]=make_float4(a,b,c,a*a+b*b+c*c);
  }
  __syncthreads();
  int id=blk*256+threadIdx.x;
  if (id>=NPTS) return;
  float px=pts[id*3+0], py=pts[id*3+1], pz=pts[id*3+2];
  float pp=px*px+py*py+pz*pz;
  float best=3.4e38f; int bi=0;
  for (int j=0;j<MN;j++){
    float4 n=nd[j];
    float d=pp+n.w-2.0f*(px*n.x+py*n.y+pz*n.z);
    if (d<best){best=d;bi=j;}
  }
  p2n[id]=bi;
}

__global__ __launch_bounds__(256) void scatter_kernel(
    const int* __restrict__ p_s, int* __restrict__ c_s, int* __restrict__ l_s,
    const int* __restrict__ p_t, int* __restrict__ c_t, int* __restrict__ l_t,
    int pb){
  int which=blockIdx.x>=pb;
  const int* p2n=which? p_t:p_s;
  int* cnt=which? c_t:c_s;
  int* list=which? l_t:l_s;
  int blk=which? blockIdx.x-pb : blockIdx.x;
  int id=blk*256+threadIdx.x;
  if (id>=NPTS) return;
  int n=p2n[id];
  int t=atomicAdd(&cnt[n],1);
  if (t<CAPL) list[(size_t)n*CAPL+t]=id;
}

// per-node kNN (fused src+tgt)
__global__ __launch_bounds__(256) void knn_kernel(
    const float* __restrict__ pts_s, const float* __restrict__ nd_s,
    const int* __restrict__ c_s, const int* __restrict__ l_s, int* __restrict__ k_s,
    const float* __restrict__ pts_t, const float* __restrict__ nd_t,
    const int* __restrict__ c_t, const int* __restrict__ l_t, int* __restrict__ k_t){
  __shared__ float ds[CAPL];
  __shared__ int is[CAPL];
  int which=blockIdx.x>=MN;
  const float* pts=which? pts_t:pts_s;
  const float* nodes=which? nd_t:nd_s;
  const int* cnt=which? c_t:c_s;
  const int* list=which? l_t:l_s;
  int* knn=which? k_t:k_s;
  int m=which? blockIdx.x-MN : blockIdx.x;
  int c=cnt[m]; if (c>CAPL) c=CAPL;
  float ax=nodes[m*3+0], ay=nodes[m*3+1], az=nodes[m*3+2];
  float nn2=ax*ax+ay*ay+az*az;
  for (int e=threadIdx.x;e<c;e+=256){
    int p=list[(size_t)m*CAPL+e];
    float px=pts[p*3+0],py=pts[p*3+1],pz=pts[p*3+2];
    float pp=px*px+py*py+pz*pz;
    ds[e]=pp+nn2-2.0f*(px*ax+py*ay+pz*az);
    is[e]=p;
  }
  for (int k=threadIdx.x;k<KK;k+=256) knn[m*KK+k]=NPTS;
  __syncthreads();
  for (int e=threadIdx.x;e<c;e+=256){
    float d=ds[e]; int p=is[e]; int r=0;
    for (int j=0;j<c;j++){
      float dj=ds[j];
      r += (dj<d || (dj==d && is[j]<p)) ? 1 : 0;
    }
    if (r<KK) knn[m*KK+r]=p;
  }
}

// coarse scores as tiled GEMM
__global__ __launch_bounds__(256) void coarse_score_kernel(
    const float* __restrict__ tf, const float* __restrict__ sf,
    const float* __restrict__ tt, const float* __restrict__ ssv,
    const int* __restrict__ cnt_t, const int* __restrict__ cnt_s, float* __restrict__ S){
  __shared__ float tas[64][64];   // [k][r]
  __shared__ float sbs[64][64];   // [k][c]
  __shared__ float tta[64], ssa[64], tva[64], sva[64];
  int bi=blockIdx.x>>4, bj=blockIdx.x&15;
  int t=threadIdx.x, r=t&63, kq=t>>6, tx=t&15, ty=t>>4;
  if (kq==0){ tta[r]=tt[bi*64+r]; tva[r]=(cnt_t[bi*64+r]>0)?1.f:0.f; }
  if (kq==1){ ssa[r]=ssv[bj*64+r]; sva[r]=(cnt_s[bj*64+r]>0)?1.f:0.f; }
  float acc[4][4]={};
  const float* ta=tf+((size_t)bi*64)*DN;
  const float* sa=sf+((size_t)bj*64)*DN;
  for (int kc=0;kc<DN;kc+=64){
    __syncthreads();
    const float* tr_=ta+(size_t)r*DN+kc+kq*16;
    const float* sr_=sa+(size_t)r*DN+kc+kq*16;
    #pragma unroll
    for (int j4=0;j4<4;j4++){
      float4 v=*(const float4*)(tr_+4*j4);
      tas[kq*16+4*j4+0][r]=v.x; tas[kq*16+4*j4+1][r]=v.y;
      tas[kq*16+4*j4+2][r]=v.z; tas[kq*16+4*j4+3][r]=v.w;
      float4 w=*(const float4*)(sr_+4*j4);
      sbs[kq*16+4*j4+0][r]=w.x; sbs[kq*16+4*j4+1][r]=w.y;
      sbs[kq*16+4*j4+2][r]=w.z; sbs[kq*16+4*j4+3][r]=w.w;
    }
    __syncthreads();
    #pragma unroll
    for (int kk=0;kk<64;kk++){
      float4 a4=*(const float4*)(&tas[kk][4*ty]);
      float4 b4=*(const float4*)(&sbs[kk][4*tx]);
      float av[4]={a4.x,a4.y,a4.z,a4.w};
      float bv[4]={b4.x,b4.y,b4.z,b4.w};
      #pragma unroll
      for (int i=0;i<4;i++)
        #pragma unroll
        for (int j=0;j<4;j++) acc[i][j]=fmaf(av[i],bv[j],acc[i][j]);
    }
  }
  __syncthreads();
  #pragma unroll
  for (int i=0;i<4;i++){
    int rr=4*ty+i;
    #pragma unroll
    for (int j=0;j<4;j++){
      int cc=4*tx+j;
      float d=tta[rr]+ssa[cc]-2.0f*acc[i][j];
      float v=expf(-d);
      S[(size_t)(bi*64+rr)*MN + bj*64+cc]=(tva[rr]>0.f && sva[cc]>0.f)? v:0.0f;
    }
  }
}

// fused row+col sums
__global__ __launch_bounds__(256) void sums_kernel(
    const float* __restrict__ S, float* __restrict__ rs, float* __restrict__ cs){
  __shared__ float red[256];
  __shared__ float red2[16][17];
  if (blockIdx.x<MN){
    int i=blockIdx.x;
    float a=0;
    for (int j=threadIdx.x;j<MN;j+=256) a+=S[(size_t)i*MN+j];
    float r=blockReduceSum256(a,red);
    if (threadIdx.x==0) rs[i]=r;
  } else {
    int j0=(blockIdx.x-MN)*16;
    int tx=threadIdx.x&15, ty=threadIdx.x>>4;
    float a=0;
    for (int i=ty;i<MN;i+=16) a+=S[(size_t)i*MN + j0+tx];
    red2[ty][tx]=a; __syncthreads();
    if (ty==0){
      float s=0;
      #pragma unroll
      for (int q=0;q<16;q++) s+=red2[q][tx];
      cs[j0+tx]=s;
    }
  }
}
// dual normalization fused with L1 histogram pass -> partial1
__global__ __launch_bounds__(256) void dualnorm_hist_kernel(
    float* __restrict__ S, const float* __restrict__ rs, const float* __restrict__ cs,
    unsigned* __restrict__ partial1){
  __shared__ unsigned lh[256];
  lh[threadIdx.x]=0u; __syncthreads();
  for (int idx=blockIdx.x*256+threadIdx.x; idx<MN*MN; idx+=gridDim.x*256){
    int i=idx>>10, j=idx&1023;
    float v=S[idx];
    v=(v/(rs[i]+EPSV))*(v/(cs[j]+EPSV));
    S[idx]=v;
    if (v>0.0f) atomicAdd(&lh[__float_as_uint(v)>>24],1u);
  }
  __syncthreads();
  partial1[blockIdx.x*256+threadIdx.x]=lh[threadIdx.x];
}

// ---------- deterministic top-k, three-level histogram (scans fused) ----------
__device__ __forceinline__ int scan_top(const unsigned* h, int k, unsigned start,
                                        unsigned* outcum){
  unsigned cum=start;
  for (int b=255;b>=0;b--){
    if (cum+h[b] >= (unsigned)k){ *outcum=cum; return b; }
    cum+=h[b];
  }
  *outcum=cum;
  return -1;
}
__device__ __forceinline__ void sum_partials(const unsigned* __restrict__ p,
                                             unsigned* h, int t){
  unsigned a=0;
  for (int i=0;i<HBLK;i++) a+=p[(size_t)i*256+t];
  h[t]=a;
}

// L2 histogram; per-block inline L1 scan
__global__ __launch_bounds__(256) void hist_fine_kernel(
    const float* __restrict__ arr, int n, int k,
    const unsigned* __restrict__ p1, unsigned* __restrict__ p2){
  __shared__ unsigned h[256];
  __shared__ unsigned lh[256];
  __shared__ unsigned cbS;
  int t=threadIdx.x;
  lh[t]=0u;
  sum_partials(p1,h,t);
  __syncthreads();
  if (t==0){
    unsigned ab; int cb=scan_top(h,k,0u,&ab);
    if (cb<0) cb=0;
    cbS=(unsigned)cb;
  }
  __syncthreads();
  unsigned CB=cbS;
  for (int i=blockIdx.x*256+t; i<n; i+=gridDim.x*256){
    float v=arr[i];
    unsigned b=__float_as_uint(v);
    if (v>0.0f && (b>>24)==CB) atomicAdd(&lh[(b>>16)&255u],1u);
  }
  __syncthreads();
  p2[blockIdx.x*256+t]=lh[t];
}
// L3 histogram; per-block inline L1+L2 scans; block0 resets cand counter
__global__ __launch_bounds__(256) void hist_fine2_kernel(
    const float* __restrict__ arr, int n, int k,
    const unsigned* __restrict__ p1, const unsigned* __restrict__ p2,
    unsigned* __restrict__ p3, unsigned* __restrict__ cnt){
  __shared__ unsigned h[256];
  __shared__ unsigned lh[256];
  __shared__ unsigned t16S;
  int t=threadIdx.x;
  if (blockIdx.x==0 && t==0) *cnt=0u;
  lh[t]=0u;
  sum_partials(p1,h,t);
  __syncthreads();
  __shared__ unsigned cbS, ab1S;
  if (t==0){
    unsigned ab; int cb=scan_top(h,k,0u,&ab);
    if (cb<0){ cb=0; ab=ab-h[0]; }
    cbS=(unsigned)cb; ab1S=ab;
  }
  __syncthreads();
  sum_partials(p2,h,t);
  __syncthreads();
  if (t==0){
    unsigned ab2; int sb=scan_top(h,k,ab1S,&ab2);
    if (sb<0) sb=0;
    t16S=cbS*256u+(unsigned)sb;
  }
  __syncthreads();
  unsigned T16=t16S;
  for (int i=blockIdx.x*256+t; i<n; i+=gridDim.x*256){
    float v=arr[i];
    unsigned b=__float_as_uint(v);
    if (v>0.0f && (b>>16)==T16) atomicAdd(&lh[(b>>8)&255u],1u);
  }
  __syncthreads();
  p3[blockIdx.x*256+t]=lh[t];
}
// compact with inline L1+L2+L3 scans (grid-stride, 256 blocks)
__global__ __launch_bounds__(256) void compact_kernel(
    const float* __restrict__ arr, int n, int k,
    const unsigned* __restrict__ p1, const unsigned* __restrict__ p2,
    const unsigned* __restrict__ p3,
    float* __restrict__ cv, int* __restrict__ ci, unsigned* __restrict__ cnt){
  __shared__ unsigned h[256];
  __shared__ unsigned cbS, ab1S, t16S, ab2S, t24S;
  int t=threadIdx.x;
  sum_partials(p1,h,t);
  __syncthreads();
  if (t==0){
    unsigned ab; int cb=scan_top(h,k,0u,&ab);
    if (cb<0){ cb=0; ab=ab-h[0]; }
    cbS=(unsigned)cb; ab1S=ab;
  }
  __syncthreads();
  sum_partials(p2,h,t);
  __syncthreads();
  if (t==0){
    unsigned ab2; int sb=scan_top(h,k,ab1S,&ab2);
    if (sb<0) sb=0;
    t16S=cbS*256u+(unsigned)sb; ab2S=ab2;
  }
  __syncthreads();
  sum_partials(p3,h,t);
  __syncthreads();
  if (t==0){
    unsigned ab3; int sb=scan_top(h,k,ab2S,&ab3);
    if (sb<0) sb=0;
    t24S=t16S*256u+(unsigned)sb;
  }
  __syncthreads();
  unsigned T=t24S;
  for (int i=blockIdx.x*256+t; i<n; i+=gridDim.x*256){
    float v=arr[i];
    if (v>0.0f && (__float_as_uint(v)>>8)>=T){
      unsigned p=atomicAdd(cnt,1u);
      if (p<CCAP){ cv[p]=v; ci[p]=i; }
    }
  }
}
// LDS-tiled exact rank (value desc, index asc)
__global__ __launch_bounds__(256) void rank_coarse_kernel(
    const float* __restrict__ cv, const int* __restrict__ ci, const unsigned* __restrict__ meta,
    int* __restrict__ ti, int* __restrict__ si){
  __shared__ __align__(16) float scv[RCH];
  __shared__ __align__(16) int sci[RCH];
  int c=(int)meta[1]; if (c>CCAP) c=CCAP;
  int t=blockIdx.x*256+threadIdx.x;
  bool act=(t<c);
  float v=0.0f; int idx=0;
  if (act){ v=cv[t]; idx=ci[t]; }
  int rk=0;
  for (int base=0;base<c;base+=RCH){
    int lim=min(RCH,c-base);
    __syncthreads();
    for (int j=threadIdx.x;j<lim;j+=256){ scv[j]=cv[base+j]; sci[j]=ci[base+j]; }
    __syncthreads();
    if (act){
      int j=0;
      for (;j+4<=lim;j+=4){
        float4 v4=*(const float4*)(scv+j);
        int4 i4=*(const int4*)(sci+j);
        rk += (v4.x>v||(v4.x==v&&i4.x<idx))?1:0;
        rk += (v4.y>v||(v4.y==v&&i4.y<idx))?1:0;
        rk += (v4.z>v||(v4.z==v&&i4.z<idx))?1:0;
        rk += (v4.w>v||(v4.w==v&&i4.w<idx))?1:0;
      }
      for (;j<lim;j++) rk += (scv[j]>v||(scv[j]==v&&sci[j]<idx))?1:0;
    }
  }
  if (act && rk<BCORR){ ti[rk]=idx/MN; si[rk]=idx%MN; }
}
__global__ __launch_bounds__(256) void rank_fine_kernel(
    const float* __restrict__ cv, const int* __restrict__ ci, const unsigned* __restrict__ meta,
    const int* __restrict__ sel_t, const int* __restrict__ sel_s,
    const float* __restrict__ tpts, const float* __restrict__ spts,
    float* __restrict__ tp, float* __restrict__ sp, float* __restrict__ cs){
  __shared__ __align__(16) float scv[RCH];
  __shared__ __align__(16) int sci[RCH];
  int c=(int)meta[1]; if (c>CCAP) c=CCAP;
  int t=blockIdx.x*256+threadIdx.x;
  bool act=(t<c);
  float v=0.0f; int idx=0;
  if (act){ v=cv[t]; idx=ci[t]; }
  int rk=0;
  for (int base=0;base<c;base+=RCH){
    int lim=min(RCH,c-base);
    __syncthreads();
    for (int j=threadIdx.x;j<lim;j+=256){ scv[j]=cv[base+j]; sci[j]=ci[base+j]; }
    __syncthreads();
    if (act){
      int j=0;
      for (;j+4<=lim;j+=4){
        float4 v4=*(const float4*)(scv+j);
        int4 i4=*(const int4*)(sci+j);
        rk += (v4.x>v||(v4.x==v&&i4.x<idx))?1:0;
        rk += (v4.y>v||(v4.y==v&&i4.y<idx))?1:0;
        rk += (v4.z>v||(v4.z==v&&i4.z<idx))?1:0;
        rk += (v4.w>v||(v4.w==v&&i4.w<idx))?1:0;
      }
      for (;j<lim;j++) rk += (scv[j]>v||(scv[j]==v&&sci[j]<idx))?1:0;
    }
  }
  if (act && rk<OUTC){
    int b=idx>>12, r=(idx>>6)&63, cc=idx&63;
    int tpi=sel_t[b*KK+r], spi=sel_s[b*KK+cc];
    float tx=0,ty=0,tz=0,sx=0,sy=0,sz=0;
    if (tpi<NPTS){ tx=tpts[tpi*3]; ty=tpts[tpi*3+1]; tz=tpts[tpi*3+2]; }
    if (spi<NPTS){ sx=spts[spi*3]; sy=spts[spi*3+1]; sz=spts[spi*3+2]; }
    tp[rk*3+0]=tx; tp[rk*3+1]=ty; tp[rk*3+2]=tz;
    sp[rk*3+0]=sx; sp[rk*3+1]=sy; sp[rk*3+2]=sz;
    cs[rk]=v;
  }
}

// ---------- patch assembly / OT / fine ----------
__global__ __launch_bounds__(256) void sel_feat_kernel(
    const int* __restrict__ ci_t, const int* __restrict__ knn_t, const float* __restrict__ ptf_t,
    const int* __restrict__ ci_s, const int* __restrict__ knn_s, const float* __restrict__ ptf_s,
    const float* __restrict__ W, const float* __restrict__ bias,
    float* __restrict__ out_t, float* __restrict__ out_s,
    int* __restrict__ sel_tO, int* __restrict__ sel_sO){
  __shared__ float Xs[64][64];   // [k][r]
  __shared__ float Ws[64][64];   // [k][o]
  __shared__ float pvf[64];
  int which=blockIdx.x>=1024;
  const int* cib=which? ci_s:ci_t;
  const int* knn=which? knn_s:knn_t;
  const float* ptf=which? ptf_s:ptf_t;
  float* out=which? out_s:out_t;
  int* sel=which? sel_sO:sel_tO;
  int blk=which? blockIdx.x-1024 : blockIdx.x;
  int bj=blk>>2, bo=blk&3;
  int t=threadIdx.x, r=t&63, kq=t>>6, tx=t&15, ty=t>>4;
  int p=knn[cib[bj]*KK+r];
  if (kq==0){
    pvf[r]=(p!=NPTS)?1.f:0.f;
    if (bo==0) sel[bj*KK+r]=p;
  }
  const float* xr=ptf+(size_t)p*DPT+kq*16;
  #pragma unroll
  for (int j4=0;j4<4;j4++){
    float4 v=(p==NPTS)? make_float4(0.f,0.f,0.f,0.f) : *(const float4*)(xr+4*j4);
    Xs[kq*16+4*j4+0][r]=v.x; Xs[kq*16+4*j4+1][r]=v.y;
    Xs[kq*16+4*j4+2][r]=v.z; Xs[kq*16+4*j4+3][r]=v.w;
  }
  const float* wr=W+(size_t)(bo*64+r)*DPT+kq*16;
  #pragma unroll
  for (int j4=0;j4<4;j4++){
    float4 w=*(const float4*)(wr+4*j4);
    Ws[kq*16+4*j4+0][r]=w.x; Ws[kq*16+4*j4+1][r]=w.y;
    Ws[kq*16+4*j4+2][r]=w.z; Ws[kq*16+4*j4+3][r]=w.w;
  }
  __syncthreads();
  float acc[4][4]={};
  #pragma unroll
  for (int kk=0;kk<64;kk++){
    float4 a4=*(const float4*)(&Xs[kk][4*ty]);
    float4 w4=*(const float4*)(&Ws[kk][4*tx]);
    float av[4]={a4.x,a4.y,a4.z,a4.w};
    float wv[4]={w4.x,w4.y,w4.z,w4.w};
    #pragma unroll
    for (int i=0;i<4;i++)
      #pragma unroll
      for (int j=0;j<4;j++) acc[i][j]=fmaf(av[i],wv[j],acc[i][j]);
  }
  #pragma unroll
  for (int i=0;i<4;i++){
    int rr=4*ty+i;
    #pragma unroll
    for (int j=0;j<4;j++){
      int oo=4*tx+j;
      float v=acc[i][j]+bias[bo*64+oo];
      out[(size_t)(bj*64+rr)*DN + bo*64+oo]= (pvf[rr]>0.f)? v : 0.0f;
    }
  }
}

// OT input P (65x65) per batch as tiled GEMM + dustbin/mask epilogue
__global__ __launch_bounds__(256) void pbuild_kernel(
    const float* __restrict__ ft, const float* __restrict__ fs,
    const int* __restrict__ sel_t, const int* __restrict__ sel_s,
    const float* __restrict__ alpha_p, float* __restrict__ P){
  __shared__ float tas[64][64];
  __shared__ float sbs[64][64];
  __shared__ float tmv[64], smv[64];
  int b=blockIdx.x, t=threadIdx.x;
  int r=t&63, kq=t>>6, tx=t&15, ty=t>>4;
  if (kq==0) tmv[r]=(sel_t[b*KK+r]!=NPTS)?1.f:0.f;
  if (kq==1) smv[r]=(sel_s[b*KK+r]!=NPTS)?1.f:0.f;
  float acc[4][4]={};
  const float* tb=ft+(size_t)b*KK*DN;
  const float* sb=fs+(size_t)b*KK*DN;
  for (int kc=0;kc<DN;kc+=64){
    __syncthreads();
    const float* tr_=tb+(size_t)r*DN+kc+kq*16;
    const float* sr_=sb+(size_t)r*DN+kc+kq*16;
    #pragma unroll
    for (int j4=0;j4<4;j4++){
      float4 v=*(const float4*)(tr_+4*j4);
      tas[kq*16+4*j4+0][r]=v.x; tas[kq*16+4*j4+1][r]=v.y;
      tas[kq*16+4*j4+2][r]=v.z; tas[kq*16+4*j4+3][r]=v.w;
      float4 w=*(const float4*)(sr_+4*j4);
      sbs[kq*16+4*j4+0][r]=w.x; sbs[kq*16+4*j4+1][r]=w.y;
      sbs[kq*16+4*j4+2][r]=w.z; sbs[kq*16+4*j4+3][r]=w.w;
    }
    __syncthreads();
    #pragma unroll
    for (int kk=0;kk<64;kk++){
      float4 a4=*(const float4*)(&tas[kk][4*ty]);
      float4 b4=*(const float4*)(&sbs[kk][4*tx]);
      float av[4]={a4.x,a4.y,a4.z,a4.w};
      float bv[4]={b4.x,b4.y,b4.z,b4.w};
      #pragma unroll
      for (int i=0;i<4;i++)
        #pragma unroll
        for (int j=0;j<4;j++) acc[i][j]=fmaf(av[i],bv[j],acc[i][j]);
    }
  }
  __syncthreads();
  float alpha=alpha_p[0];
  float* Pb=P+(size_t)b*65*65;
  #pragma unroll
  for (int i=0;i<4;i++){
    int rr=4*ty+i;
    bool tok=tmv[rr]>0.f;
    #pragma unroll
    for (int j=0;j<4;j++){
      int cc=4*tx+j;
      bool invm=(!tok)||(smv[cc]<=0.f);
      Pb[rr*65+cc]= invm ? NEGV : acc[i][j]*0.0625f;
    }
  }
  if (t<64){
    Pb[64*65+t]=(smv[t]<=0.f)? NEGV : alpha;
    Pb[t*65+64]=(tmv[t]<=0.f)? NEGV : alpha;
  }
  if (t==64) Pb[64*65+64]=alpha;
}

// Sinkhorn linear-domain, 4 waves per batch, column-split, 2 barriers/iter.
// Chunk broadcasts via v_readlane (SALU, wave-uniform index).
__global__ __launch_bounds__(256,1) void ot_kernel(
    float* __restrict__ P, const int* __restrict__ sel_t, const int* __restrict__ sel_s){
  __shared__ float Ps[4225];
  __shared__ __align__(16) float partU[4][72], partV[4][72];
  __shared__ __align__(16) float pu64[4], pusv[4], pv64[4], pvsv[4];
  __shared__ float ufs[65], vfs[65];
  int b=blockIdx.x, t=threadIdx.x, w=t>>6, l=t&63;
  float* Pg=P+(size_t)b*4225;
  for (int e=t;e<4225;e+=256) Ps[e]=Pg[e];
  bool rv=(sel_t[b*KK+l]!=NPTS);
  bool cv=(sel_s[b*KK+l]!=NPTS);
  int nr=(int)__popcll(__ballot(rv));
  int nc=(int)__popcll(__ballot(cv));
  float inv=1.0f/(float)(nr+nc);
  float nrm=-logf((float)(nr+nc));
  float mu_l=inv, nu_l=inv, mu64=(float)nc*inv, nu64=(float)nr*inv;
  bool anyInvR=(nr<KK), anyInvC=(nc<KK);
  __syncthreads();
  const int c0=16*w;
  float aQ[16], bQ[16], r64Q[16], c64Q[16];
  #pragma unroll
  for (int j=0;j<16;j++){
    aQ[j]  =expf(Ps[l*65+c0+j]);
    bQ[j]  =expf(Ps[(c0+j)*65+l]);
    r64Q[j]=expf(Ps[64*65+c0+j]);
    c64Q[j]=expf(Ps[(c0+j)*65+64]);
  }
  float a64=expf(Ps[l*65+64]);
  float b64v=expf(Ps[64*65+l]);
  float k6464=expf(Ps[4224]);
  float U_l, V_l=1.0f, U64, V64=1.0f;

  for (int it=0; it<OTI; ++it){
    float p0=0,p1f=0,p2f=0,p3=0, d0=0,d1=0,d2=0,d3=0, z0=0,z1=0,z2=0,z3=0;
    #pragma unroll
    for (int j4=0;j4<4;j4++){
      float v0=__int_as_float(__builtin_amdgcn_readlane(__float_as_int(V_l), c0+4*j4+0));
      float v1=__int_as_float(__builtin_amdgcn_readlane(__float_as_int(V_l), c0+4*j4+1));
      float v2=__int_as_float(__builtin_amdgcn_readlane(__float_as_int(V_l), c0+4*j4+2));
      float v3=__int_as_float(__builtin_amdgcn_readlane(__float_as_int(V_l), c0+4*j4+3));
      p0=fmaf(aQ[4*j4+0],v0,p0); p1f=fmaf(aQ[4*j4+1],v1,p1f);
      p2f=fmaf(aQ[4*j4+2],v2,p2f); p3=fmaf(aQ[4*j4+3],v3,p3);
      d0=fmaf(r64Q[4*j4+0],v0,d0); d1=fmaf(r64Q[4*j4+1],v1,d1);
      d2=fmaf(r64Q[4*j4+2],v2,d2); d3=fmaf(r64Q[4*j4+3],v3,d3);
      z0+=v0; z1+=v1; z2+=v2; z3+=v3;
    }
    partU[w][l]=(p0+p1f)+(p2f+p3);
    if (l==0){ pu64[w]=(d0+d1)+(d2+d3); pusv[w]=(z0+z1)+(z2+z3); }
    __syncthreads();
    {
      float s=partU[0][l]+partU[1][l]+partU[2][l]+partU[3][l];
      float4 d4=*(const float4*)pu64;
      float srow=s+a64*V64;
      float s64=(d4.x+d4.y)+(d4.z+d4.w)+k6464*V64;
      U64=mu64/s64;
      if (anyInvR){
        float4 z4=*(const float4*)pusv;
        float sv=(z4.x+z4.y)+(z4.z+z4.w)+V64;
        U_l = rv ? (mu_l/srow) : (1.0f/sv);
      } else U_l = mu_l/srow;
    }
    float q0=0,q1=0,q2=0,q3=0, e0=0,e1=0,e2=0,e3=0, y0=0,y1=0,y2=0,y3=0;
    #pragma unroll
    for (int j4=0;j4<4;j4++){
      float u0=__int_as_float(__builtin_amdgcn_readlane(__float_as_int(U_l), c0+4*j4+0));
      float u1=__int_as_float(__builtin_amdgcn_readlane(__float_as_int(U_l), c0+4*j4+1));
      float u2=__int_as_float(__builtin_amdgcn_readlane(__float_as_int(U_l), c0+4*j4+2));
      float u3=__int_as_float(__builtin_amdgcn_readlane(__float_as_int(U_l), c0+4*j4+3));
      q0=fmaf(bQ[4*j4+0],u0,q0); q1=fmaf(bQ[4*j4+1],u1,q1);
      q2=fmaf(bQ[4*j4+2],u2,q2); q3=fmaf(bQ[4*j4+3],u3,q3);
      e0=fmaf(c64Q[4*j4+0],u0,e0); e1=fmaf(c64Q[4*j4+1],u1,e1);
      e2=fmaf(c64Q[4*j4+2],u2,e2); e3=fmaf(c64Q[4*j4+3],u3,e3);
      y0+=u0; y1+=u1; y2+=u2; y3+=u3;
    }
    partV[w][l]=(q0+q1)+(q2+q3);
    if (l==0){ pv64[w]=(e0+e1)+(e2+e3); pvsv[w]=(y0+y1)+(y2+y3); }
    __syncthreads();
    {
      float sc=partV[0][l]+partV[1][l]+partV[2][l]+partV[3][l];
      float4 e4=*(const float4*)pv64;
      float scol=sc+b64v*U64;
      float s64v=(e4.x+e4.y)+(e4.z+e4.w)+k6464*U64;
      V64=nu64/s64v;
      if (anyInvC){
        float4 y4=*(const float4*)pvsv;
        float su=(y4.x+y4.y)+(y4.z+y4.w)+U64;
        V_l = cv ? (nu_l/scol) : (1.0f/su);
      } else V_l = nu_l/scol;
    }
  }
  if (w==0){
    ufs[l]=logf(U_l); vfs[l]=logf(V_l);
    if (l==0){ ufs[64]=logf(U64); vfs[64]=logf(V64); }
  }
  __syncthreads();
  for (int e=t;e<4225;e+=256){
    int r=e/65, c=e-65*r;
    Pg[e]=Ps[e]+ufs[r]+vfs[c]-nrm;
  }
}

// fine prep fused with L1 histogram of the masked scores -> partial1
__global__ __launch_bounds__(256) void fineprep_kernel(
    const float* __restrict__ P, const int* __restrict__ sel_t, const int* __restrict__ sel_s,
    float* __restrict__ smout, unsigned* __restrict__ partial1){
  __shared__ float s[KK*KK];
  __shared__ unsigned long long rowm[KK], colm[KK];
  __shared__ int tmk[KK], smk[KK];
  __shared__ unsigned lh[256];
  int b=blockIdx.x, t=threadIdx.x;
  lh[t]=0u;
  const float* Pb=P+(size_t)b*65*65;
  for (int e=t;e<KK*KK;e+=256){
    int r=e>>6, c=e&63;
    s[e]=expf(Pb[r*65+c]);
  }
  if (t<KK){ tmk[t]=(sel_t[b*KK+t]!=NPTS); smk[t]=(sel_s[b*KK+t]!=NPTS); }
  __syncthreads();
  if (t<KK){
    float v1=-1,v2=-1,v3=-1; int i1=0,i2=0,i3=0;
    const float* row=s+t*KK;
    for (int c=0;c<KK;c++){ float v=row[c];
      if (v>v1){v3=v2;i3=i2;v2=v1;i2=i1;v1=v;i1=c;}
      else if (v>v2){v3=v2;i3=i2;v2=v;i2=c;}
      else if (v>v3){v3=v;i3=c;}
    }
    rowm[t]=(1ULL<<i1)|(1ULL<<i2)|(1ULL<<i3);
  } else if (t<2*KK){
    int c=t-KK;
    float v1=-1,v2=-1,v3=-1; int i1=0,i2=0,i3=0;
    for (int r=0;r<KK;r++){ float v=s[r*KK+c];
      if (v>v1){v3=v2;i3=i2;v2=v1;i2=i1;v1=v;i1=r;}
      else if (v>v2){v3=v2;i3=i2;v2=v;i2=r;}
      else if (v>v3){v3=v;i3=r;}
    }
    colm[c]=(1ULL<<i1)|(1ULL<<i2)|(1ULL<<i3);
  }
  __syncthreads();
  for (int e=t;e<KK*KK;e+=256){
    int r=e>>6, c=e&63;
    float v=s[e];
    bool keep = ((rowm[r]>>c)&1ULL) && ((colm[c]>>r)&1ULL) && (v>0.05f) && tmk[r] && smk[c];
    float o= keep? v : 0.0f;
    smout[(size_t)b*KK*KK+e]=o;
    if (o>0.0f) atomicAdd(&lh[__float_as_uint(o)>>24],1u);
  }
  __syncthreads();
  partial1[b*256+t]=lh[t];
}

extern "C" void kernel_launch(void* const* d_in, const int* in_sizes, int n_in,
                              void* d_out, int out_size, void* d_ws, size_t ws_size,
                              hipStream_t stream){
  const float* src_pts=(const float*)d_in[0];
  const float* tgt_pts=(const float*)d_in[1];
  const float* src_pf =(const float*)d_in[2];
  const float* tgt_pf =(const float*)d_in[3];
  const float* src_nf =(const float*)d_in[4];
  const float* tgt_nf =(const float*)d_in[5];
  const float* src_nx =(const float*)d_in[6];
  const float* tgt_nx =(const float*)d_in[7];
  const float* cw=(const float*)d_in[8];
  const float* cb=(const float*)d_in[9];
  const float* fw=(const float*)d_in[10];
  const float* fb=(const float*)d_in[11];
  const float* alpha=(const float*)d_in[12];

  char* ws=(char*)d_ws;
  size_t off=0;
  auto A=[&](size_t bytes)->char*{
    char* p=ws+off; off+=(bytes+255)&~(size_t)255; return p; };

  float* tf    =(float*)A((size_t)MN*DN*4);
  float* sfb   =(float*)A((size_t)MN*DN*4);
  float* nfr   =(float*)A((size_t)2*MN*DN*4);
  float* tt    =(float*)A(MN*4);
  float* ssv   =(float*)A(MN*4);
  int*   p2n_s =(int*)A((size_t)NPTS*4);
  int*   p2n_t =(int*)A((size_t)NPTS*4);
  int*   cnt_s =(int*)A(MN*4);
  int*   cnt_t =(int*)A(MN*4);
  int*   list_s=(int*)A((size_t)MN*CAPL*4);
  int*   list_t=(int*)A((size_t)MN*CAPL*4);
  int*   knn_s =(int*)A((size_t)MN*KK*4);
  int*   knn_t =(int*)A((size_t)MN*KK*4);
  float* Smat  =(float*)A((size_t)MN*MN*4);
  unsigned* partial1=(unsigned*)A((size_t)HBLK*256*4);
  unsigned* partial2=(unsigned*)A((size_t)HBLK*256*4);
  unsigned* partial3=(unsigned*)A((size_t)HBLK*256*4);
  unsigned* meta=(unsigned*)A(256);
  float* cand_v=(float*)A((size_t)CCAP*4);
  int*   cand_i=(int*)A((size_t)CCAP*4);
  int*   ci_t  =(int*)A(BCORR*4);
  int*   ci_s  =(int*)A(BCORR*4);
  int*   sel_t =(int*)A((size_t)BCORR*KK*4);
  int*   sel_s =(int*)A((size_t)BCORR*KK*4);
  float* feat_t=(float*)A((size_t)BCORR*KK*DN*4);
  float* feat_s=(float*)A((size_t)BCORR*KK*DN*4);
  float* smf   =(float*)A((size_t)BCORR*KK*KK*4);
  float* rs    =(float*)A(MN*4);
  float* csum  =(float*)A(MN*4);

  float* out=(float*)d_out;
  float* msout=out;
  float* tpout=out+(size_t)BCORR*65*65;
  float* spout=tpout+(size_t)OUTC*3;
  float* csout=spout+(size_t)OUTC*3;

  const int PB=(NPTS+255)/256;

  zero_all_kernel<<<28,256,0,stream>>>(cnt_s,cnt_t,ci_t,ci_s,tpout);
  node_gemm_kernel<<<128,256,0,stream>>>(tgt_nf,src_nf,cw,cb,nfr);
  node_norm_kernel<<<2*MN,256,0,stream>>>(nfr,tf,sfb,tt,ssv);
  p2n_kernel<<<2*PB,256,0,stream>>>(src_pts,src_nx,p2n_s,tgt_pts,tgt_nx,p2n_t,PB);
  scatter_kernel<<<2*PB,256,0,stream>>>(p2n_s,cnt_s,list_s,p2n_t,cnt_t,list_t,PB);
  knn_kernel<<<2*MN,256,0,stream>>>(src_pts,src_nx,cnt_s,list_s,knn_s,
                                    tgt_pts,tgt_nx,cnt_t,list_t,knn_t);

  coarse_score_kernel<<<256,256,0,stream>>>(tf,sfb,tt,ssv,cnt_t,cnt_s,Smat);
  sums_kernel<<<MN+64,256,0,stream>>>(Smat,rs,csum);
  dualnorm_hist_kernel<<<HBLK,256,0,stream>>>(Smat,rs,csum,partial1);

  hist_fine_kernel<<<HBLK,256,0,stream>>>(Smat,MN*MN,BCORR,partial1,partial2);
  hist_fine2_kernel<<<HBLK,256,0,stream>>>(Smat,MN*MN,BCORR,partial1,partial2,partial3,meta+1);
  compact_kernel<<<256,256,0,stream>>>(Smat,MN*MN,BCORR,partial1,partial2,partial3,
                                       cand_v,cand_i,meta+1);
  rank_coarse_kernel<<<CCAP/256,256,0,stream>>>(cand_v,cand_i,meta,ci_t,ci_s);

  sel_feat_kernel<<<2048,256,0,stream>>>(ci_t,knn_t,tgt_pf, ci_s,knn_s,src_pf,
                                         fw,fb,feat_t,feat_s,sel_t,sel_s);

  pbuild_kernel<<<BCORR,256,0,stream>>>(feat_t,feat_s,sel_t,sel_s,alpha,msout);
  ot_kernel<<<BCORR,256,0,stream>>>(msout,sel_t,sel_s);

  fineprep_kernel<<<BCORR,256,0,stream>>>(msout,sel_t,sel_s,smf,partial1);
  hist_fine_kernel<<<HBLK,256,0,stream>>>(smf,BCORR*KK*KK,OUTC,partial1,partial2);
  hist_fine2_kernel<<<HBLK,256,0,stream>>>(smf,BCORR*KK*KK,OUTC,partial1,partial2,partial3,meta+1);
  compact_kernel<<<256,256,0,stream>>>(smf,BCORR*KK*KK,OUTC,partial1,partial2,partial3,
                                       cand_v,cand_i,meta+1);
  rank_fine_kernel<<<CCAP/256,256,0,stream>>>(cand_v,cand_i,meta,sel_t,sel_s,
                                              tgt_pts,src_pts,tpout,spout,csout);
}

// Round 16
// 529.655 us; speedup vs baseline: 1.3081x; 1.0222x over previous
//
#include <hip/hip_runtime.h>
#include <math.h>

#define NPTS 50000
#define MN 1024
#define KK 64
#define DPT 64
#define DN 256
#define BCORR 256
#define OUTC 1024
#define OTI 100
#define NEGV (-1e4f)
#define EPSV 1e-8f
#define CAPL 512
#define CCAP 16384
#define HBLK 256   // blocks for histogram passes (and partial-buffer depth)
#define RCH 2048   // rank-kernel LDS chunk

// ---------------- utility ----------------
__global__ void zero_all_kernel(int* cnt_s, int* cnt_t, int* ci_t, int* ci_s,
                                float* tpout){
  int t=blockIdx.x*256+threadIdx.x;
  if (t<MN){ cnt_s[t]=0; cnt_t[t]=0; }
  if (t<BCORR){ ci_t[t]=0; ci_s[t]=0; }
  for (int i=t;i<OUTC*3*2+OUTC;i+=gridDim.x*256) tpout[i]=0.0f;
}

__device__ __forceinline__ float blockReduceSum256(float v, float* red){
  int t=threadIdx.x;
  red[t]=v; __syncthreads();
  #pragma unroll
  for (int s=128;s>0;s>>=1){ if(t<s) red[t]+=red[t+s]; __syncthreads(); }
  float r=red[0]; __syncthreads();
  return r;
}

// wave-aggregated LDS histogram add: one atomic per wave when all active
// lanes share a bucket (clustered-value fast path); exact counts always.
__device__ __forceinline__ void hist_add_agg(unsigned* lh, bool act, unsigned bkt){
  unsigned long long ma=__ballot(act);
  if (ma==0ULL) return;
  unsigned b0=__shfl(bkt, 0, 64);
  unsigned long long m=__ballot(act && bkt==b0);
  int lane=threadIdx.x&63;
  if (m==ma){
    int leader=__ffsll((long long)ma)-1;
    if (act && lane==leader) atomicAdd(&lh[b0],(unsigned)__popcll(ma));
  } else if (act){
    atomicAdd(&lh[bkt],1u);
  }
}

// node feature GEMM: raw = [X_tgt;X_src](2048x256) @ W^T + b  (tiled, coalesced)
__global__ __launch_bounds__(256) void node_gemm_kernel(
    const float* __restrict__ xt, const float* __restrict__ xs_,
    const float* __restrict__ W, const float* __restrict__ bias,
    float* __restrict__ raw){
  __shared__ float Xs[64][64];   // [k][r]
  __shared__ float Ws[64][64];   // [k][o]
  int bi=blockIdx.x>>2, bo=blockIdx.x&3;
  const float* x=(bi<16)? xt:xs_;
  int rowbase=(bi&15)*64;
  int t=threadIdx.x, r=t&63, kq=t>>6, tx=t&15, ty=t>>4;
  float acc[4][4]={};
  for (int kc=0;kc<DN;kc+=64){
    __syncthreads();
    const float* xr=x+(size_t)(rowbase+r)*DN+kc+kq*16;
    const float* wr=W+(size_t)(bo*64+r)*DN+kc+kq*16;
    #pragma unroll
    for (int j4=0;j4<4;j4++){
      float4 v=*(const float4*)(xr+4*j4);
      Xs[kq*16+4*j4+0][r]=v.x; Xs[kq*16+4*j4+1][r]=v.y;
      Xs[kq*16+4*j4+2][r]=v.z; Xs[kq*16+4*j4+3][r]=v.w;
      float4 w=*(const float4*)(wr+4*j4);
      Ws[kq*16+4*j4+0][r]=w.x; Ws[kq*16+4*j4+1][r]=w.y;
      Ws[kq*16+4*j4+2][r]=w.z; Ws[kq*16+4*j4+3][r]=w.w;
    }
    __syncthreads();
    #pragma unroll
    for (int kk=0;kk<64;kk++){
      float4 a4=*(const float4*)(&Xs[kk][4*ty]);
      float4 w4=*(const float4*)(&Ws[kk][4*tx]);
      float av[4]={a4.x,a4.y,a4.z,a4.w};
      float wv[4]={w4.x,w4.y,w4.z,w4.w};
      #pragma unroll
      for (int i=0;i<4;i++)
        #pragma unroll
        for (int j=0;j<4;j++) acc[i][j]=fmaf(av[i],wv[j],acc[i][j]);
    }
  }
  size_t gr=(size_t)(bi*64)*DN;
  #pragma unroll
  for (int i=0;i<4;i++){
    int rr=4*ty+i;
    #pragma unroll
    for (int j=0;j<4;j++){
      int oo=4*tx+j;
      raw[gr+(size_t)rr*DN+bo*64+oo]=acc[i][j]+bias[bo*64+oo];
    }
  }
}
// normalize: out = raw/||raw||, sq = sum(out^2)
__global__ __launch_bounds__(256) void node_norm_kernel(
    const float* __restrict__ raw,
    float* __restrict__ outt, float* __restrict__ outs,
    float* __restrict__ sqt, float* __restrict__ sqs){
  __shared__ float red[256];
  int m=blockIdx.x, i=threadIdx.x;
  float* out=(m<MN)? outt:outs;
  float* sq=(m<MN)? sqt:sqs;
  int mm=(m<MN)? m:m-MN;
  float acc=raw[(size_t)m*DN+i];
  float ssq=blockReduceSum256(acc*acc,red);
  float o=acc/sqrtf(ssq);
  out[mm*DN+i]=o;
  float s2=blockReduceSum256(o*o,red);
  if(i==0) sq[mm]=s2;
}

// fused nearest-node + scatter (src+tgt); nodes packed float4 (x,y,z,|n|^2)
__global__ __launch_bounds__(256) void p2n_scatter_kernel(
    const float* __restrict__ pts_s, const float* __restrict__ nd_s,
    int* __restrict__ c_s, int* __restrict__ l_s,
    const float* __restrict__ pts_t, const float* __restrict__ nd_t,
    int* __restrict__ c_t, int* __restrict__ l_t,
    int pb){
  __shared__ __align__(16) float4 nd[MN];
  int which=blockIdx.x>=pb;
  const float* pts=which? pts_t:pts_s;
  const float* nodes=which? nd_t:nd_s;
  int* cnt=which? c_t:c_s;
  int* list=which? l_t:l_s;
  int blk=which? blockIdx.x-pb : blockIdx.x;
  for (int j=threadIdx.x;j<MN;j+=256){
    float a=nodes[j*3+0], b=nodes[j*3+1], c=nodes[j*3+2];
    nd[j]=make_float4(a,b,c,a*a+b*b+c*c);
  }
  __syncthreads();
  int id=blk*256+threadIdx.x;
  if (id>=NPTS) return;
  float px=pts[id*3+0], py=pts[id*3+1], pz=pts[id*3+2];
  float pp=px*px+py*py+pz*pz;
  float best=3.4e38f; int bi=0;
  for (int j=0;j<MN;j++){
    float4 n=nd[j];
    float d=pp+n.w-2.0f*(px*n.x+py*n.y+pz*n.z);
    if (d<best){best=d;bi=j;}
  }
  int slot=atomicAdd(&cnt[bi],1);
  if (slot<CAPL) list[(size_t)bi*CAPL+slot]=id;
}

// per-node kNN (fused src+tgt)
__global__ __launch_bounds__(256) void knn_kernel(
    const float* __restrict__ pts_s, const float* __restrict__ nd_s,
    const int* __restrict__ c_s, const int* __restrict__ l_s, int* __restrict__ k_s,
    const float* __restrict__ pts_t, const float* __restrict__ nd_t,
    const int* __restrict__ c_t, const int* __restrict__ l_t, int* __restrict__ k_t){
  __shared__ float ds[CAPL];
  __shared__ int is[CAPL];
  int which=blockIdx.x>=MN;
  const float* pts=which? pts_t:pts_s;
  const float* nodes=which? nd_t:nd_s;
  const int* cnt=which? c_t:c_s;
  const int* list=which? l_t:l_s;
  int* knn=which? k_t:k_s;
  int m=which? blockIdx.x-MN : blockIdx.x;
  int c=cnt[m]; if (c>CAPL) c=CAPL;
  float ax=nodes[m*3+0], ay=nodes[m*3+1], az=nodes[m*3+2];
  float nn2=ax*ax+ay*ay+az*az;
  for (int e=threadIdx.x;e<c;e+=256){
    int p=list[(size_t)m*CAPL+e];
    float px=pts[p*3+0],py=pts[p*3+1],pz=pts[p*3+2];
    float pp=px*px+py*py+pz*pz;
    ds[e]=pp+nn2-2.0f*(px*ax+py*ay+pz*az);
    is[e]=p;
  }
  for (int k=threadIdx.x;k<KK;k+=256) knn[m*KK+k]=NPTS;
  __syncthreads();
  for (int e=threadIdx.x;e<c;e+=256){
    float d=ds[e]; int p=is[e]; int r=0;
    for (int j=0;j<c;j++){
      float dj=ds[j];
      r += (dj<d || (dj==d && is[j]<p)) ? 1 : 0;
    }
    if (r<KK) knn[m*KK+r]=p;
  }
}

// coarse scores as tiled GEMM
__global__ __launch_bounds__(256) void coarse_score_kernel(
    const float* __restrict__ tf, const float* __restrict__ sf,
    const float* __restrict__ tt, const float* __restrict__ ssv,
    const int* __restrict__ cnt_t, const int* __restrict__ cnt_s, float* __restrict__ S){
  __shared__ float tas[64][64];   // [k][r]
  __shared__ float sbs[64][64];   // [k][c]
  __shared__ float tta[64], ssa[64], tva[64], sva[64];
  int bi=blockIdx.x>>4, bj=blockIdx.x&15;
  int t=threadIdx.x, r=t&63, kq=t>>6, tx=t&15, ty=t>>4;
  if (kq==0){ tta[r]=tt[bi*64+r]; tva[r]=(cnt_t[bi*64+r]>0)?1.f:0.f; }
  if (kq==1){ ssa[r]=ssv[bj*64+r]; sva[r]=(cnt_s[bj*64+r]>0)?1.f:0.f; }
  float acc[4][4]={};
  const float* ta=tf+((size_t)bi*64)*DN;
  const float* sa=sf+((size_t)bj*64)*DN;
  for (int kc=0;kc<DN;kc+=64){
    __syncthreads();
    const float* tr_=ta+(size_t)r*DN+kc+kq*16;
    const float* sr_=sa+(size_t)r*DN+kc+kq*16;
    #pragma unroll
    for (int j4=0;j4<4;j4++){
      float4 v=*(const float4*)(tr_+4*j4);
      tas[kq*16+4*j4+0][r]=v.x; tas[kq*16+4*j4+1][r]=v.y;
      tas[kq*16+4*j4+2][r]=v.z; tas[kq*16+4*j4+3][r]=v.w;
      float4 w=*(const float4*)(sr_+4*j4);
      sbs[kq*16+4*j4+0][r]=w.x; sbs[kq*16+4*j4+1][r]=w.y;
      sbs[kq*16+4*j4+2][r]=w.z; sbs[kq*16+4*j4+3][r]=w.w;
    }
    __syncthreads();
    #pragma unroll
    for (int kk=0;kk<64;kk++){
      float4 a4=*(const float4*)(&tas[kk][4*ty]);
      float4 b4=*(const float4*)(&sbs[kk][4*tx]);
      float av[4]={a4.x,a4.y,a4.z,a4.w};
      float bv[4]={b4.x,b4.y,b4.z,b4.w};
      #pragma unroll
      for (int i=0;i<4;i++)
        #pragma unroll
        for (int j=0;j<4;j++) acc[i][j]=fmaf(av[i],bv[j],acc[i][j]);
    }
  }
  __syncthreads();
  #pragma unroll
  for (int i=0;i<4;i++){
    int rr=4*ty+i;
    #pragma unroll
    for (int j=0;j<4;j++){
      int cc=4*tx+j;
      float d=tta[rr]+ssa[cc]-2.0f*acc[i][j];
      float v=expf(-d);
      S[(size_t)(bi*64+rr)*MN + bj*64+cc]=(tva[rr]>0.f && sva[cc]>0.f)? v:0.0f;
    }
  }
}

// fused row+col sums
__global__ __launch_bounds__(256) void sums_kernel(
    const float* __restrict__ S, float* __restrict__ rs, float* __restrict__ cs){
  __shared__ float red[256];
  __shared__ float red2[16][17];
  if (blockIdx.x<MN){
    int i=blockIdx.x;
    float a=0;
    for (int j=threadIdx.x;j<MN;j+=256) a+=S[(size_t)i*MN+j];
    float r=blockReduceSum256(a,red);
    if (threadIdx.x==0) rs[i]=r;
  } else {
    int j0=(blockIdx.x-MN)*16;
    int tx=threadIdx.x&15, ty=threadIdx.x>>4;
    float a=0;
    for (int i=ty;i<MN;i+=16) a+=S[(size_t)i*MN + j0+tx];
    red2[ty][tx]=a; __syncthreads();
    if (ty==0){
      float s=0;
      #pragma unroll
      for (int q=0;q<16;q++) s+=red2[q][tx];
      cs[j0+tx]=s;
    }
  }
}
// dual normalization fused with L1 histogram pass (wave-aggregated atomics)
__global__ __launch_bounds__(256) void dualnorm_hist_kernel(
    float* __restrict__ S, const float* __restrict__ rs, const float* __restrict__ cs,
    unsigned* __restrict__ partial1){
  __shared__ unsigned lh[256];
  lh[threadIdx.x]=0u; __syncthreads();
  for (int idx=blockIdx.x*256+threadIdx.x; idx<MN*MN; idx+=gridDim.x*256){
    int i=idx>>10, j=idx&1023;
    float v=S[idx];
    v=(v/(rs[i]+EPSV))*(v/(cs[j]+EPSV));
    S[idx]=v;
    bool act=(v>0.0f);
    unsigned bkt=act? (__float_as_uint(v)>>24) : 0xFFFFFFFFu;
    hist_add_agg(lh,act,bkt);
  }
  __syncthreads();
  partial1[blockIdx.x*256+threadIdx.x]=lh[threadIdx.x];
}

// ---------- deterministic top-k, three-level histogram (scans fused) ----------
__device__ __forceinline__ int scan_top(const unsigned* h, int k, unsigned start,
                                        unsigned* outcum){
  unsigned cum=start;
  for (int b=255;b>=0;b--){
    if (cum+h[b] >= (unsigned)k){ *outcum=cum; return b; }
    cum+=h[b];
  }
  *outcum=cum;
  return -1;
}
__device__ __forceinline__ void sum_partials(const unsigned* __restrict__ p,
                                             unsigned* h, int t){
  unsigned a=0;
  for (int i=0;i<HBLK;i++) a+=p[(size_t)i*256+t];
  h[t]=a;
}

// L2 histogram; per-block inline L1 scan
__global__ __launch_bounds__(256) void hist_fine_kernel(
    const float* __restrict__ arr, int n, int k,
    const unsigned* __restrict__ p1, unsigned* __restrict__ p2){
  __shared__ unsigned h[256];
  __shared__ unsigned lh[256];
  __shared__ unsigned cbS;
  int t=threadIdx.x;
  lh[t]=0u;
  sum_partials(p1,h,t);
  __syncthreads();
  if (t==0){
    unsigned ab; int cb=scan_top(h,k,0u,&ab);
    if (cb<0) cb=0;
    cbS=(unsigned)cb;
  }
  __syncthreads();
  unsigned CB=cbS;
  for (int i=blockIdx.x*256+t; i<n; i+=gridDim.x*256){
    float v=arr[i];
    unsigned b=__float_as_uint(v);
    bool act=(v>0.0f && (b>>24)==CB);
    hist_add_agg(lh,act,(b>>16)&255u);
  }
  __syncthreads();
  p2[blockIdx.x*256+t]=lh[t];
}
// L3 histogram; per-block inline L1+L2 scans; block0 resets cand counter
__global__ __launch_bounds__(256) void hist_fine2_kernel(
    const float* __restrict__ arr, int n, int k,
    const unsigned* __restrict__ p1, const unsigned* __restrict__ p2,
    unsigned* __restrict__ p3, unsigned* __restrict__ cnt){
  __shared__ unsigned h[256];
  __shared__ unsigned lh[256];
  __shared__ unsigned t16S;
  int t=threadIdx.x;
  if (blockIdx.x==0 && t==0) *cnt=0u;
  lh[t]=0u;
  sum_partials(p1,h,t);
  __syncthreads();
  __shared__ unsigned cbS, ab1S;
  if (t==0){
    unsigned ab; int cb=scan_top(h,k,0u,&ab);
    if (cb<0){ cb=0; ab=ab-h[0]; }
    cbS=(unsigned)cb; ab1S=ab;
  }
  __syncthreads();
  sum_partials(p2,h,t);
  __syncthreads();
  if (t==0){
    unsigned ab2; int sb=scan_top(h,k,ab1S,&ab2);
    if (sb<0) sb=0;
    t16S=cbS*256u+(unsigned)sb;
  }
  __syncthreads();
  unsigned T16=t16S;
  for (int i=blockIdx.x*256+t; i<n; i+=gridDim.x*256){
    float v=arr[i];
    unsigned b=__float_as_uint(v);
    bool act=(v>0.0f && (b>>16)==T16);
    hist_add_agg(lh,act,(b>>8)&255u);
  }
  __syncthreads();
  p3[blockIdx.x*256+t]=lh[t];
}
// compact with inline L1+L2+L3 scans (grid-stride, 256 blocks)
__global__ __launch_bounds__(256) void compact_kernel(
    const float* __restrict__ arr, int n, int k,
    const unsigned* __restrict__ p1, const unsigned* __restrict__ p2,
    const unsigned* __restrict__ p3,
    float* __restrict__ cv, int* __restrict__ ci, unsigned* __restrict__ cnt){
  __shared__ unsigned h[256];
  __shared__ unsigned cbS, ab1S, t16S, ab2S, t24S;
  int t=threadIdx.x;
  sum_partials(p1,h,t);
  __syncthreads();
  if (t==0){
    unsigned ab; int cb=scan_top(h,k,0u,&ab);
    if (cb<0){ cb=0; ab=ab-h[0]; }
    cbS=(unsigned)cb; ab1S=ab;
  }
  __syncthreads();
  sum_partials(p2,h,t);
  __syncthreads();
  if (t==0){
    unsigned ab2; int sb=scan_top(h,k,ab1S,&ab2);
    if (sb<0) sb=0;
    t16S=cbS*256u+(unsigned)sb; ab2S=ab2;
  }
  __syncthreads();
  sum_partials(p3,h,t);
  __syncthreads();
  if (t==0){
    unsigned ab3; int sb=scan_top(h,k,ab2S,&ab3);
    if (sb<0) sb=0;
    t24S=t16S*256u+(unsigned)sb;
  }
  __syncthreads();
  unsigned T=t24S;
  for (int i=blockIdx.x*256+t; i<n; i+=gridDim.x*256){
    float v=arr[i];
    if (v>0.0f && (__float_as_uint(v)>>8)>=T){
      unsigned p=atomicAdd(cnt,1u);
      if (p<CCAP){ cv[p]=v; ci[p]=i; }
    }
  }
}
// LDS-tiled exact rank (value desc, index asc)
__global__ __launch_bounds__(256) void rank_coarse_kernel(
    const float* __restrict__ cv, const int* __restrict__ ci, const unsigned* __restrict__ meta,
    int* __restrict__ ti, int* __restrict__ si){
  __shared__ __align__(16) float scv[RCH];
  __shared__ __align__(16) int sci[RCH];
  int c=(int)meta[1]; if (c>CCAP) c=CCAP;
  int t=blockIdx.x*256+threadIdx.x;
  bool act=(t<c);
  float v=0.0f; int idx=0;
  if (act){ v=cv[t]; idx=ci[t]; }
  int rk=0;
  for (int base=0;base<c;base+=RCH){
    int lim=min(RCH,c-base);
    __syncthreads();
    for (int j=threadIdx.x;j<lim;j+=256){ scv[j]=cv[base+j]; sci[j]=ci[base+j]; }
    __syncthreads();
    if (act){
      int j=0;
      for (;j+4<=lim;j+=4){
        float4 v4=*(const float4*)(scv+j);
        int4 i4=*(const int4*)(sci+j);
        rk += (v4.x>v||(v4.x==v&&i4.x<idx))?1:0;
        rk += (v4.y>v||(v4.y==v&&i4.y<idx))?1:0;
        rk += (v4.z>v||(v4.z==v&&i4.z<idx))?1:0;
        rk += (v4.w>v||(v4.w==v&&i4.w<idx))?1:0;
      }
      for (;j<lim;j++) rk += (scv[j]>v||(scv[j]==v&&sci[j]<idx))?1:0;
    }
  }
  if (act && rk<BCORR){ ti[rk]=idx/MN; si[rk]=idx%MN; }
}
__global__ __launch_bounds__(256) void rank_fine_kernel(
    const float* __restrict__ cv, const int* __restrict__ ci, const unsigned* __restrict__ meta,
    const int* __restrict__ sel_t, const int* __restrict__ sel_s,
    const float* __restrict__ tpts, const float* __restrict__ spts,
    float* __restrict__ tp, float* __restrict__ sp, float* __restrict__ cs){
  __shared__ __align__(16) float scv[RCH];
  __shared__ __align__(16) int sci[RCH];
  int c=(int)meta[1]; if (c>CCAP) c=CCAP;
  int t=blockIdx.x*256+threadIdx.x;
  bool act=(t<c);
  float v=0.0f; int idx=0;
  if (act){ v=cv[t]; idx=ci[t]; }
  int rk=0;
  for (int base=0;base<c;base+=RCH){
    int lim=min(RCH,c-base);
    __syncthreads();
    for (int j=threadIdx.x;j<lim;j+=256){ scv[j]=cv[base+j]; sci[j]=ci[base+j]; }
    __syncthreads();
    if (act){
      int j=0;
      for (;j+4<=lim;j+=4){
        float4 v4=*(const float4*)(scv+j);
        int4 i4=*(const int4*)(sci+j);
        rk += (v4.x>v||(v4.x==v&&i4.x<idx))?1:0;
        rk += (v4.y>v||(v4.y==v&&i4.y<idx))?1:0;
        rk += (v4.z>v||(v4.z==v&&i4.z<idx))?1:0;
        rk += (v4.w>v||(v4.w==v&&i4.w<idx))?1:0;
      }
      for (;j<lim;j++) rk += (scv[j]>v||(scv[j]==v&&sci[j]<idx))?1:0;
    }
  }
  if (act && rk<OUTC){
    int b=idx>>12, r=(idx>>6)&63, cc=idx&63;
    int tpi=sel_t[b*KK+r], spi=sel_s[b*KK+cc];
    float tx=0,ty=0,tz=0,sx=0,sy=0,sz=0;
    if (tpi<NPTS){ tx=tpts[tpi*3]; ty=tpts[tpi*3+1]; tz=tpts[tpi*3+2]; }
    if (spi<NPTS){ sx=spts[spi*3]; sy=spts[spi*3+1]; sz=spts[spi*3+2]; }
    tp[rk*3+0]=tx; tp[rk*3+1]=ty; tp[rk*3+2]=tz;
    sp[rk*3+0]=sx; sp[rk*3+1]=sy; sp[rk*3+2]=sz;
    cs[rk]=v;
  }
}

// ---------- patch assembly / OT / fine ----------
__global__ __launch_bounds__(256) void sel_feat_kernel(
    const int* __restrict__ ci_t, const int* __restrict__ knn_t, const float* __restrict__ ptf_t,
    const int* __restrict__ ci_s, const int* __restrict__ knn_s, const float* __restrict__ ptf_s,
    const float* __restrict__ W, const float* __restrict__ bias,
    float* __restrict__ out_t, float* __restrict__ out_s,
    int* __restrict__ sel_tO, int* __restrict__ sel_sO){
  __shared__ float Xs[64][64];   // [k][r]
  __shared__ float Ws[64][64];   // [k][o]
  __shared__ float pvf[64];
  int which=blockIdx.x>=1024;
  const int* cib=which? ci_s:ci_t;
  const int* knn=which? knn_s:knn_t;
  const float* ptf=which? ptf_s:ptf_t;
  float* out=which? out_s:out_t;
  int* sel=which? sel_sO:sel_tO;
  int blk=which? blockIdx.x-1024 : blockIdx.x;
  int bj=blk>>2, bo=blk&3;
  int t=threadIdx.x, r=t&63, kq=t>>6, tx=t&15, ty=t>>4;
  int p=knn[cib[bj]*KK+r];
  if (kq==0){
    pvf[r]=(p!=NPTS)?1.f:0.f;
    if (bo==0) sel[bj*KK+r]=p;
  }
  const float* xr=ptf+(size_t)p*DPT+kq*16;
  #pragma unroll
  for (int j4=0;j4<4;j4++){
    float4 v=(p==NPTS)? make_float4(0.f,0.f,0.f,0.f) : *(const float4*)(xr+4*j4);
    Xs[kq*16+4*j4+0][r]=v.x; Xs[kq*16+4*j4+1][r]=v.y;
    Xs[kq*16+4*j4+2][r]=v.z; Xs[kq*16+4*j4+3][r]=v.w;
  }
  const float* wr=W+(size_t)(bo*64+r)*DPT+kq*16;
  #pragma unroll
  for (int j4=0;j4<4;j4++){
    float4 w=*(const float4*)(wr+4*j4);
    Ws[kq*16+4*j4+0][r]=w.x; Ws[kq*16+4*j4+1][r]=w.y;
    Ws[kq*16+4*j4+2][r]=w.z; Ws[kq*16+4*j4+3][r]=w.w;
  }
  __syncthreads();
  float acc[4][4]={};
  #pragma unroll
  for (int kk=0;kk<64;kk++){
    float4 a4=*(const float4*)(&Xs[kk][4*ty]);
    float4 w4=*(const float4*)(&Ws[kk][4*tx]);
    float av[4]={a4.x,a4.y,a4.z,a4.w};
    float wv[4]={w4.x,w4.y,w4.z,w4.w};
    #pragma unroll
    for (int i=0;i<4;i++)
      #pragma unroll
      for (int j=0;j<4;j++) acc[i][j]=fmaf(av[i],wv[j],acc[i][j]);
  }
  #pragma unroll
  for (int i=0;i<4;i++){
    int rr=4*ty+i;
    #pragma unroll
    for (int j=0;j<4;j++){
      int oo=4*tx+j;
      float v=acc[i][j]+bias[bo*64+oo];
      out[(size_t)(bj*64+rr)*DN + bo*64+oo]= (pvf[rr]>0.f)? v : 0.0f;
    }
  }
}

// OT input P (65x65) per batch as tiled GEMM + dustbin/mask epilogue
__global__ __launch_bounds__(256) void pbuild_kernel(
    const float* __restrict__ ft, const float* __restrict__ fs,
    const int* __restrict__ sel_t, const int* __restrict__ sel_s,
    const float* __restrict__ alpha_p, float* __restrict__ P){
  __shared__ float tas[64][64];
  __shared__ float sbs[64][64];
  __shared__ float tmv[64], smv[64];
  int b=blockIdx.x, t=threadIdx.x;
  int r=t&63, kq=t>>6, tx=t&15, ty=t>>4;
  if (kq==0) tmv[r]=(sel_t[b*KK+r]!=NPTS)?1.f:0.f;
  if (kq==1) smv[r]=(sel_s[b*KK+r]!=NPTS)?1.f:0.f;
  float acc[4][4]={};
  const float* tb=ft+(size_t)b*KK*DN;
  const float* sb=fs+(size_t)b*KK*DN;
  for (int kc=0;kc<DN;kc+=64){
    __syncthreads();
    const float* tr_=tb+(size_t)r*DN+kc+kq*16;
    const float* sr_=sb+(size_t)r*DN+kc+kq*16;
    #pragma unroll
    for (int j4=0;j4<4;j4++){
      float4 v=*(const float4*)(tr_+4*j4);
      tas[kq*16+4*j4+0][r]=v.x; tas[kq*16+4*j4+1][r]=v.y;
      tas[kq*16+4*j4+2][r]=v.z; tas[kq*16+4*j4+3][r]=v.w;
      float4 w=*(const float4*)(sr_+4*j4);
      sbs[kq*16+4*j4+0][r]=w.x; sbs[kq*16+4*j4+1][r]=w.y;
      sbs[kq*16+4*j4+2][r]=w.z; sbs[kq*16+4*j4+3][r]=w.w;
    }
    __syncthreads();
    #pragma unroll
    for (int kk=0;kk<64;kk++){
      float4 a4=*(const float4*)(&tas[kk][4*ty]);
      float4 b4=*(const float4*)(&sbs[kk][4*tx]);
      float av[4]={a4.x,a4.y,a4.z,a4.w};
      float bv[4]={b4.x,b4.y,b4.z,b4.w};
      #pragma unroll
      for (int i=0;i<4;i++)
        #pragma unroll
        for (int j=0;j<4;j++) acc[i][j]=fmaf(av[i],bv[j],acc[i][j]);
    }
  }
  __syncthreads();
  float alpha=alpha_p[0];
  float* Pb=P+(size_t)b*65*65;
  #pragma unroll
  for (int i=0;i<4;i++){
    int rr=4*ty+i;
    bool tok=tmv[rr]>0.f;
    #pragma unroll
    for (int j=0;j<4;j++){
      int cc=4*tx+j;
      bool invm=(!tok)||(smv[cc]<=0.f);
      Pb[rr*65+cc]= invm ? NEGV : acc[i][j]*0.0625f;
    }
  }
  if (t<64){
    Pb[64*65+t]=(smv[t]<=0.f)? NEGV : alpha;
    Pb[t*65+64]=(tmv[t]<=0.f)? NEGV : alpha;
  }
  if (t==64) Pb[64*65+64]=alpha;
}

// Sinkhorn linear-domain, 4 waves per batch, column-split, 2 barriers/iter.
__global__ __launch_bounds__(256,1) void ot_kernel(
    float* __restrict__ P, const int* __restrict__ sel_t, const int* __restrict__ sel_s){
  __shared__ float Ps[4225];
  __shared__ __align__(16) float partU[4][72], partV[4][72];
  __shared__ __align__(16) float pu64[4], pusv[4], pv64[4], pvsv[4];
  __shared__ float ufs[65], vfs[65];
  int b=blockIdx.x, t=threadIdx.x, w=t>>6, l=t&63;
  float* Pg=P+(size_t)b*4225;
  for (int e=t;e<4225;e+=256) Ps[e]=Pg[e];
  bool rv=(sel_t[b*KK+l]!=NPTS);
  bool cv=(sel_s[b*KK+l]!=NPTS);
  int nr=(int)__popcll(__ballot(rv));
  int nc=(int)__popcll(__ballot(cv));
  float inv=1.0f/(float)(nr+nc);
  float nrm=-logf((float)(nr+nc));
  float mu_l=inv, nu_l=inv, mu64=(float)nc*inv, nu64=(float)nr*inv;
  bool anyInvR=(nr<KK), anyInvC=(nc<KK);
  __syncthreads();
  const int c0=16*w;
  float aQ[16], bQ[16], r64Q[16], c64Q[16];
  #pragma unroll
  for (int j=0;j<16;j++){
    aQ[j]  =expf(Ps[l*65+c0+j]);
    bQ[j]  =expf(Ps[(c0+j)*65+l]);
    r64Q[j]=expf(Ps[64*65+c0+j]);
    c64Q[j]=expf(Ps[(c0+j)*65+64]);
  }
  float a64=expf(Ps[l*65+64]);
  float b64v=expf(Ps[64*65+l]);
  float k6464=expf(Ps[4224]);
  float U_l, V_l=1.0f, U64, V64=1.0f;

  for (int it=0; it<OTI; ++it){
    float p0=0,p1f=0,p2f=0,p3=0, d0=0,d1=0,d2=0,d3=0, z0=0,z1=0,z2=0,z3=0;
    #pragma unroll
    for (int j4=0;j4<4;j4++){
      float v0=__int_as_float(__builtin_amdgcn_readlane(__float_as_int(V_l), c0+4*j4+0));
      float v1=__int_as_float(__builtin_amdgcn_readlane(__float_as_int(V_l), c0+4*j4+1));
      float v2=__int_as_float(__builtin_amdgcn_readlane(__float_as_int(V_l), c0+4*j4+2));
      float v3=__int_as_float(__builtin_amdgcn_readlane(__float_as_int(V_l), c0+4*j4+3));
      p0=fmaf(aQ[4*j4+0],v0,p0); p1f=fmaf(aQ[4*j4+1],v1,p1f);
      p2f=fmaf(aQ[4*j4+2],v2,p2f); p3=fmaf(aQ[4*j4+3],v3,p3);
      d0=fmaf(r64Q[4*j4+0],v0,d0); d1=fmaf(r64Q[4*j4+1],v1,d1);
      d2=fmaf(r64Q[4*j4+2],v2,d2); d3=fmaf(r64Q[4*j4+3],v3,d3);
      z0+=v0; z1+=v1; z2+=v2; z3+=v3;
    }
    partU[w][l]=(p0+p1f)+(p2f+p3);
    if (l==0){ pu64[w]=(d0+d1)+(d2+d3); pusv[w]=(z0+z1)+(z2+z3); }
    __syncthreads();
    {
      float s=partU[0][l]+partU[1][l]+partU[2][l]+partU[3][l];
      float4 d4=*(const float4*)pu64;
      float srow=s+a64*V64;
      float s64=(d4.x+d4.y)+(d4.z+d4.w)+k6464*V64;
      U64=mu64/s64;
      if (anyInvR){
        float4 z4=*(const float4*)pusv;
        float sv=(z4.x+z4.y)+(z4.z+z4.w)+V64;
        U_l = rv ? (mu_l/srow) : (1.0f/sv);
      } else U_l = mu_l/srow;
    }
    float q0=0,q1=0,q2=0,q3=0, e0=0,e1=0,e2=0,e3=0, y0=0,y1=0,y2=0,y3=0;
    #pragma unroll
    for (int j4=0;j4<4;j4++){
      float u0=__int_as_float(__builtin_amdgcn_readlane(__float_as_int(U_l), c0+4*j4+0));
      float u1=__int_as_float(__builtin_amdgcn_readlane(__float_as_int(U_l), c0+4*j4+1));
      float u2=__int_as_float(__builtin_amdgcn_readlane(__float_as_int(U_l), c0+4*j4+2));
      float u3=__int_as_float(__builtin_amdgcn_readlane(__float_as_int(U_l), c0+4*j4+3));
      q0=fmaf(bQ[4*j4+0],u0,q0); q1=fmaf(bQ[4*j4+1],u1,q1);
      q2=fmaf(bQ[4*j4+2],u2,q2); q3=fmaf(bQ[4*j4+3],u3,q3);
      e0=fmaf(c64Q[4*j4+0],u0,e0); e1=fmaf(c64Q[4*j4+1],u1,e1);
      e2=fmaf(c64Q[4*j4+2],u2,e2); e3=fmaf(c64Q[4*j4+3],u3,e3);
      y0+=u0; y1+=u1; y2+=u2; y3+=u3;
    }
    partV[w][l]=(q0+q1)+(q2+q3);
    if (l==0){ pv64[w]=(e0+e1)+(e2+e3); pvsv[w]=(y0+y1)+(y2+y3); }
    __syncthreads();
    {
      float sc=partV[0][l]+partV[1][l]+partV[2][l]+partV[3][l];
      float4 e4=*(const float4*)pv64;
      float scol=sc+b64v*U64;
      float s64v=(e4.x+e4.y)+(e4.z+e4.w)+k6464*U64;
      V64=nu64/s64v;
      if (anyInvC){
        float4 y4=*(const float4*)pvsv;
        float su=(y4.x+y4.y)+(y4.z+y4.w)+U64;
        V_l = cv ? (nu_l/scol) : (1.0f/su);
      } else V_l = nu_l/scol;
    }
  }
  if (w==0){
    ufs[l]=logf(U_l); vfs[l]=logf(V_l);
    if (l==0){ ufs[64]=logf(U64); vfs[64]=logf(V64); }
  }
  __syncthreads();
  for (int e=t;e<4225;e+=256){
    int r=e/65, c=e-65*r;
    Pg[e]=Ps[e]+ufs[r]+vfs[c]-nrm;
  }
}

// fine prep fused with L1 histogram of the masked scores -> partial1
__global__ __launch_bounds__(256) void fineprep_kernel(
    const float* __restrict__ P, const int* __restrict__ sel_t, const int* __restrict__ sel_s,
    float* __restrict__ smout, unsigned* __restrict__ partial1){
  __shared__ float s[KK*KK];
  __shared__ unsigned long long rowm[KK], colm[KK];
  __shared__ int tmk[KK], smk[KK];
  __shared__ unsigned lh[256];
  int b=blockIdx.x, t=threadIdx.x;
  lh[t]=0u;
  const float* Pb=P+(size_t)b*65*65;
  for (int e=t;e<KK*KK;e+=256){
    int r=e>>6, c=e&63;
    s[e]=expf(Pb[r*65+c]);
  }
  if (t<KK){ tmk[t]=(sel_t[b*KK+t]!=NPTS); smk[t]=(sel_s[b*KK+t]!=NPTS); }
  __syncthreads();
  if (t<KK){
    float v1=-1,v2=-1,v3=-1; int i1=0,i2=0,i3=0;
    const float* row=s+t*KK;
    for (int c=0;c<KK;c++){ float v=row[c];
      if (v>v1){v3=v2;i3=i2;v2=v1;i2=i1;v1=v;i1=c;}
      else if (v>v2){v3=v2;i3=i2;v2=v;i2=c;}
      else if (v>v3){v3=v;i3=c;}
    }
    rowm[t]=(1ULL<<i1)|(1ULL<<i2)|(1ULL<<i3);
  } else if (t<2*KK){
    int c=t-KK;
    float v1=-1,v2=-1,v3=-1; int i1=0,i2=0,i3=0;
    for (int r=0;r<KK;r++){ float v=s[r*KK+c];
      if (v>v1){v3=v2;i3=i2;v2=v1;i2=i1;v1=v;i1=r;}
      else if (v>v2){v3=v2;i3=i2;v2=v;i2=r;}
      else if (v>v3){v3=v;i3=r;}
    }
    colm[c]=(1ULL<<i1)|(1ULL<<i2)|(1ULL<<i3);
  }
  __syncthreads();
  for (int e=t;e<KK*KK;e+=256){
    int r=e>>6, c=e&63;
    float v=s[e];
    bool keep = ((rowm[r]>>c)&1ULL) && ((colm[c]>>r)&1ULL) && (v>0.05f) && tmk[r] && smk[c];
    float o= keep? v : 0.0f;
    smout[(size_t)b*KK*KK+e]=o;
    if (o>0.0f) atomicAdd(&lh[__float_as_uint(o)>>24],1u);
  }
  __syncthreads();
  partial1[b*256+t]=lh[t];
}

extern "C" void kernel_launch(void* const* d_in, const int* in_sizes, int n_in,
                              void* d_out, int out_size, void* d_ws, size_t ws_size,
                              hipStream_t stream){
  const float* src_pts=(const float*)d_in[0];
  const float* tgt_pts=(const float*)d_in[1];
  const float* src_pf =(const float*)d_in[2];
  const float* tgt_pf =(const float*)d_in[3];
  const float* src_nf =(const float*)d_in[4];
  const float* tgt_nf =(const float*)d_in[5];
  const float* src_nx =(const float*)d_in[6];
  const float* tgt_nx =(const float*)d_in[7];
  const float* cw=(const float*)d_in[8];
  const float* cb=(const float*)d_in[9];
  const float* fw=(const float*)d_in[10];
  const float* fb=(const float*)d_in[11];
  const float* alpha=(const float*)d_in[12];

  char* ws=(char*)d_ws;
  size_t off=0;
  auto A=[&](size_t bytes)->char*{
    char* p=ws+off; off+=(bytes+255)&~(size_t)255; return p; };

  float* tf    =(float*)A((size_t)MN*DN*4);
  float* sfb   =(float*)A((size_t)MN*DN*4);
  float* nfr   =(float*)A((size_t)2*MN*DN*4);
  float* tt    =(float*)A(MN*4);
  float* ssv   =(float*)A(MN*4);
  int*   cnt_s =(int*)A(MN*4);
  int*   cnt_t =(int*)A(MN*4);
  int*   list_s=(int*)A((size_t)MN*CAPL*4);
  int*   list_t=(int*)A((size_t)MN*CAPL*4);
  int*   knn_s =(int*)A((size_t)MN*KK*4);
  int*   knn_t =(int*)A((size_t)MN*KK*4);
  float* Smat  =(float*)A((size_t)MN*MN*4);
  unsigned* partial1=(unsigned*)A((size_t)HBLK*256*4);
  unsigned* partial2=(unsigned*)A((size_t)HBLK*256*4);
  unsigned* partial3=(unsigned*)A((size_t)HBLK*256*4);
  unsigned* meta=(unsigned*)A(256);
  float* cand_v=(float*)A((size_t)CCAP*4);
  int*   cand_i=(int*)A((size_t)CCAP*4);
  int*   ci_t  =(int*)A(BCORR*4);
  int*   ci_s  =(int*)A(BCORR*4);
  int*   sel_t =(int*)A((size_t)BCORR*KK*4);
  int*   sel_s =(int*)A((size_t)BCORR*KK*4);
  float* feat_t=(float*)A((size_t)BCORR*KK*DN*4);
  float* feat_s=(float*)A((size_t)BCORR*KK*DN*4);
  float* smf   =(float*)A((size_t)BCORR*KK*KK*4);
  float* rs    =(float*)A(MN*4);
  float* csum  =(float*)A(MN*4);

  float* out=(float*)d_out;
  float* msout=out;
  float* tpout=out+(size_t)BCORR*65*65;
  float* spout=tpout+(size_t)OUTC*3;
  float* csout=spout+(size_t)OUTC*3;

  const int PB=(NPTS+255)/256;

  zero_all_kernel<<<28,256,0,stream>>>(cnt_s,cnt_t,ci_t,ci_s,tpout);
  node_gemm_kernel<<<128,256,0,stream>>>(tgt_nf,src_nf,cw,cb,nfr);
  node_norm_kernel<<<2*MN,256,0,stream>>>(nfr,tf,sfb,tt,ssv);
  p2n_scatter_kernel<<<2*PB,256,0,stream>>>(src_pts,src_nx,cnt_s,list_s,
                                            tgt_pts,tgt_nx,cnt_t,list_t,PB);
  knn_kernel<<<2*MN,256,0,stream>>>(src_pts,src_nx,cnt_s,list_s,knn_s,
                                    tgt_pts,tgt_nx,cnt_t,list_t,knn_t);

  coarse_score_kernel<<<256,256,0,stream>>>(tf,sfb,tt,ssv,cnt_t,cnt_s,Smat);
  sums_kernel<<<MN+64,256,0,stream>>>(Smat,rs,csum);
  dualnorm_hist_kernel<<<HBLK,256,0,stream>>>(Smat,rs,csum,partial1);

  hist_fine_kernel<<<HBLK,256,0,stream>>>(Smat,MN*MN,BCORR,partial1,partial2);
  hist_fine2_kernel<<<HBLK,256,0,stream>>>(Smat,MN*MN,BCORR,partial1,partial2,partial3,meta+1);
  compact_kernel<<<256,256,0,stream>>>(Smat,MN*MN,BCORR,partial1,partial2,partial3,
                                       cand_v,cand_i,meta+1);
  rank_coarse_kernel<<<CCAP/256,256,0,stream>>>(cand_v,cand_i,meta,ci_t,ci_s);

  sel_feat_kernel<<<2048,256,0,stream>>>(ci_t,knn_t,tgt_pf, ci_s,knn_s,src_pf,
                                         fw,fb,feat_t,feat_s,sel_t,sel_s);

  pbuild_kernel<<<BCORR,256,0,stream>>>(feat_t,feat_s,sel_t,sel_s,alpha,msout);
  ot_kernel<<<BCORR,256,0,stream>>>(msout,sel_t,sel_s);

  fineprep_kernel<<<BCORR,256,0,stream>>>(msout,sel_t,sel_s,smf,partial1);
  hist_fine_kernel<<<HBLK,256,0,stream>>>(smf,BCORR*KK*KK,OUTC,partial1,partial2);
  hist_fine2_kernel<<<HBLK,256,0,stream>>>(smf,BCORR*KK*KK,OUTC,partial1,partial2,partial3,meta+1);
  compact_kernel<<<256,256,0,stream>>>(smf,BCORR*KK*KK,OUTC,partial1,partial2,partial3,
                                       cand_v,cand_i,meta+1);
  rank_fine_kernel<<<CCAP/256,256,0,stream>>>(cand_v,cand_i,meta,sel_t,sel_s,
                                              tgt_pts,src_pts,tpout,spout,csout);
}